// Round 1
// baseline (1584.263 us; speedup 1.0000x reference)
//
#include <hip/hip_runtime.h>
#include <math.h>

#define B_   2
#define T_   2048
#define DIM_ 1040
#define H_   16
#define HD_  64
#define HD1_ 65
#define NELEM (B_*T_*DIM_)   // 4,259,840 floats per (b,t,dim) tensor

// ---------------------------------------------------------------------------
// GEMM: C[M,N] = A[M,K] @ B[N,K]^T   (row-major, K multiple of 16, M mult 64)
// 64x64 tile per 256-thread block, 4x4 micro-tile per thread.
// ---------------------------------------------------------------------------
__global__ __launch_bounds__(256)
void gemm_nt(const float* __restrict__ A, const float* __restrict__ Bm,
             float* __restrict__ C, int M, int N, int K)
{
    __shared__ float As[16][68];
    __shared__ float Bs[16][68];

    const int tid  = threadIdx.x;
    const int tx   = tid & 15, ty = tid >> 4;
    const int m0   = blockIdx.y * 64;
    const int n0   = blockIdx.x * 64;
    const int lrow = tid >> 2;   // 0..63
    const int lseg = tid & 3;    // 0..3  (each seg = 4 consecutive k)

    const float* Aptr = A + (size_t)(m0 + lrow) * K + lseg * 4;
    const bool   bval = (n0 + lrow) < N;
    const float* Bptr = Bm + (size_t)(bval ? (n0 + lrow) : 0) * K + lseg * 4;

    float acc[4][4] = {};

    for (int k0 = 0; k0 < K; k0 += 16) {
        float4 av = *(const float4*)(Aptr + k0);
        float4 bv = make_float4(0.f, 0.f, 0.f, 0.f);
        if (bval) bv = *(const float4*)(Bptr + k0);

        __syncthreads();   // previous compute done reading LDS
        As[lseg*4+0][lrow] = av.x;
        As[lseg*4+1][lrow] = av.y;
        As[lseg*4+2][lrow] = av.z;
        As[lseg*4+3][lrow] = av.w;
        Bs[lseg*4+0][lrow] = bv.x;
        Bs[lseg*4+1][lrow] = bv.y;
        Bs[lseg*4+2][lrow] = bv.z;
        Bs[lseg*4+3][lrow] = bv.w;
        __syncthreads();   // tile staged

        #pragma unroll
        for (int kk = 0; kk < 16; ++kk) {
            float a[4], b[4];
            #pragma unroll
            for (int i = 0; i < 4; ++i) a[i] = As[kk][ty + 16*i];
            #pragma unroll
            for (int j = 0; j < 4; ++j) b[j] = Bs[kk][tx + 16*j];
            #pragma unroll
            for (int i = 0; i < 4; ++i)
                #pragma unroll
                for (int j = 0; j < 4; ++j)
                    acc[i][j] += a[i] * b[j];
        }
    }

    #pragma unroll
    for (int i = 0; i < 4; ++i) {
        const int m = m0 + ty + 16*i;
        #pragma unroll
        for (int j = 0; j < 4; ++j) {
            const int n = n0 + tx + 16*j;
            if (n < N) C[(size_t)m * N + n] = acc[i][j];
        }
    }
}

// ---------------------------------------------------------------------------
// Hyperbolic rotary, in-place on q or k buffer of shape (B,T,H,HD1).
// One wave (64 lanes) per (b,t,h) vector. x0 is recomputed; original x0 unused.
// ---------------------------------------------------------------------------
__global__ __launch_bounds__(256)
void rotary_k(float* __restrict__ X)
{
    const int wid  = (blockIdx.x * 256 + threadIdx.x) >> 6;  // global wave id
    const int lane = threadIdx.x & 63;
    if (wid >= B_ * T_ * H_) return;

    const int h  = wid & (H_ - 1);
    const int bt = wid >> 4;          // b*T + t
    const int t  = bt & (T_ - 1);
    float* base = X + (size_t)bt * DIM_ + h * HD1_;

    const int j = lane & 31;
    // ref: inv_freq = 1/10000^(2j/(HD-2eps));  (HD-2eps) rounds to 64.0 in fp32
    const float pw   = powf(10000.0f, (float)j * (1.0f / 32.0f));
    const float invf = 1.0f / pw;
    const float fr   = (float)t * invf;   // fp32 outer product, same as ref
    const float cs   = cosf(fr);
    const float sn   = sinf(fr);

    const float x1 = base[1 + j];
    const float x2 = base[33 + j];

    float rot = (lane < 32) ? (x1 * cs + x2 * sn)     // y1
                            : (x2 * cs - x1 * sn);    // y2
    rot = fminf(fmaxf(rot, -1000.0f), 1000.0f);

    float sq = rot * rot;
    #pragma unroll
    for (int off = 32; off >= 1; off >>= 1)
        sq += __shfl_xor(sq, off, 64);
    sq = fminf(fmaxf(sq, 0.0f), 1.0e6f);

    const float x0 = sqrtf((1.0f + sq) + 1.0e-6f);

    base[1 + lane] = rot;
    if (lane == 0) base[0] = x0;
}

// ---------------------------------------------------------------------------
// Attention: per block = one (b,h) and 64 q rows; stream K/V in 64-wide tiles.
// logits = (q_sp.k_sp - q0*k0)/8 clipped +-100 (sign folded: qtT[0] = -q0),
// full (non-causal) online softmax, acc = sum p*v, normalized at the end.
// LDS: qtT (transposed q tile), kv (shared K-transposed / V buffer), st scores.
// ---------------------------------------------------------------------------
__global__ __launch_bounds__(256)
void attn_k(const float* __restrict__ Q, const float* __restrict__ K,
            const float* __restrict__ V, float* __restrict__ Y)
{
    __shared__ float qtT[HD1_][68];   // [c][r]
    __shared__ float kv [HD1_][68];   // K phase: [c][s]; V phase: [s][c]
    __shared__ float st [64][68];     // scores then exp(scores)
    __shared__ float mrow[64], lrow[64], arow[64];

    const int tid = threadIdx.x;
    const int tx  = tid & 15, ty = tid >> 4;
    const int bh  = blockIdx.y;            // b*H + h
    const int b   = bh >> 4, h = bh & 15;
    const int q0r = blockIdx.x * 64;
    const size_t hb = (size_t)b * T_ * DIM_ + (size_t)h * HD1_;

    for (int idx = tid; idx < 64 * HD1_; idx += 256) {
        const int r = idx / HD1_, c = idx - r * HD1_;
        const float val = Q[hb + (size_t)(q0r + r) * DIM_ + c];
        qtT[c][r] = (c == 0) ? -val : val;   // fold Lorentz sign
    }
    if (tid < 64) { mrow[tid] = -1.0e30f; lrow[tid] = 0.0f; }

    float acc[4][5] = {};   // rows ty+16i, dims tx+16j (j==4 valid only tx==0)

    for (int s0 = 0; s0 < T_; s0 += 64) {
        __syncthreads();   // prev PV done reading kv/st (and q-load on iter 0)

        // ---- stage K tile transposed: kv[c][s] ----
        for (int idx = tid; idx < 64 * HD1_; idx += 256) {
            const int r = idx / HD1_, c = idx - r * HD1_;
            kv[c][r] = K[hb + (size_t)(s0 + r) * DIM_ + c];
        }
        __syncthreads();   // K ready

        // ---- scores: rows ty+16i, cols tx*4+jj ----
        float sc[4][4] = {};
        for (int kk = 0; kk < HD1_; ++kk) {
            float a[4];
            #pragma unroll
            for (int i = 0; i < 4; ++i) a[i] = qtT[kk][ty + 16*i];
            const float4 b4 = *(const float4*)&kv[kk][tx * 4];
            #pragma unroll
            for (int i = 0; i < 4; ++i) {
                sc[i][0] += a[i] * b4.x;
                sc[i][1] += a[i] * b4.y;
                sc[i][2] += a[i] * b4.z;
                sc[i][3] += a[i] * b4.w;
            }
        }
        #pragma unroll
        for (int i = 0; i < 4; ++i) {
            float4 o;
            o.x = fminf(fmaxf(sc[i][0] * 0.125f, -100.0f), 100.0f);
            o.y = fminf(fmaxf(sc[i][1] * 0.125f, -100.0f), 100.0f);
            o.z = fminf(fmaxf(sc[i][2] * 0.125f, -100.0f), 100.0f);
            o.w = fminf(fmaxf(sc[i][3] * 0.125f, -100.0f), 100.0f);
            *(float4*)&st[ty + 16*i][tx * 4] = o;
        }
        __syncthreads();   // scores ready; kv free for V

        // ---- online softmax row stats (4 threads per row) ----
        {
            const int rr = tid >> 2, qq = tid & 3;
            float mx = -1.0e30f;
            #pragma unroll
            for (int c = 0; c < 16; ++c) mx = fmaxf(mx, st[rr][qq*16 + c]);
            mx = fmaxf(mx, __shfl_xor(mx, 1, 64));
            mx = fmaxf(mx, __shfl_xor(mx, 2, 64));
            const float mold = mrow[rr];
            const float mnew = fmaxf(mold, mx);
            float sum = 0.0f;
            #pragma unroll
            for (int c = 0; c < 16; ++c) {
                const float p = expf(st[rr][qq*16 + c] - mnew);
                st[rr][qq*16 + c] = p;
                sum += p;
            }
            sum += __shfl_xor(sum, 1, 64);
            sum += __shfl_xor(sum, 2, 64);
            if (qq == 0) {
                const float al = expf(mold - mnew);
                arow[rr] = al;
                mrow[rr] = mnew;
                lrow[rr] = lrow[rr] * al + sum;
            }
        }

        // ---- stage V tile row-major into kv: kv[s][c] ----
        for (int idx = tid; idx < 64 * HD1_; idx += 256) {
            const int r = idx / HD1_, c = idx - r * HD1_;
            kv[r][c] = V[hb + (size_t)(s0 + r) * DIM_ + c];
        }
        __syncthreads();   // exp(st), stats, V all ready

        // ---- PV accumulate ----
        {
            float al[4];
            #pragma unroll
            for (int i = 0; i < 4; ++i) al[i] = arow[ty + 16*i];
            #pragma unroll
            for (int i = 0; i < 4; ++i)
                #pragma unroll
                for (int j = 0; j < 5; ++j) acc[i][j] *= al[i];

            for (int kk = 0; kk < 64; ++kk) {
                float p[4];
                #pragma unroll
                for (int i = 0; i < 4; ++i) p[i] = st[ty + 16*i][kk];
                const float v0 = kv[kk][tx];
                const float v1 = kv[kk][tx + 16];
                const float v2 = kv[kk][tx + 32];
                const float v3 = kv[kk][tx + 48];
                const float v4 = kv[kk][64];
                #pragma unroll
                for (int i = 0; i < 4; ++i) {
                    acc[i][0] += p[i] * v0;
                    acc[i][1] += p[i] * v1;
                    acc[i][2] += p[i] * v2;
                    acc[i][3] += p[i] * v3;
                    acc[i][4] += p[i] * v4;
                }
            }
        }
    }

    #pragma unroll
    for (int i = 0; i < 4; ++i) {
        const int r = ty + 16*i;
        const float li = lrow[r];
        const size_t rowb = hb + (size_t)(q0r + r) * DIM_;
        #pragma unroll
        for (int j = 0; j < 5; ++j) {
            const int d = tx + 16*j;
            if (d < HD1_) Y[rowb + d] = acc[i][j] / li;
        }
    }
}

// ---------------------------------------------------------------------------
extern "C" void kernel_launch(void* const* d_in, const int* in_sizes, int n_in,
                              void* d_out, int out_size, void* d_ws, size_t ws_size,
                              hipStream_t stream)
{
    const float* x  = (const float*)d_in[0];
    const float* Wq = (const float*)d_in[1];
    const float* Wk = (const float*)d_in[2];
    const float* Wv = (const float*)d_in[3];
    const float* Wp = (const float*)d_in[4];

    float* q = (float*)d_ws;
    float* k = q + NELEM;
    float* v = k + NELEM;
    float* y = v + NELEM;
    float* out = (float*)d_out;

    const int M = B_ * T_;                 // 4096
    dim3 blk(256);
    dim3 gg((DIM_ + 63) / 64, M / 64);     // (17, 64)

    gemm_nt<<<gg, blk, 0, stream>>>(x, Wq, q, M, DIM_, DIM_);
    gemm_nt<<<gg, blk, 0, stream>>>(x, Wk, k, M, DIM_, DIM_);
    gemm_nt<<<gg, blk, 0, stream>>>(x, Wv, v, M, DIM_, DIM_);

    rotary_k<<<(B_ * T_ * H_) / 4, blk, 0, stream>>>(q);
    rotary_k<<<(B_ * T_ * H_) / 4, blk, 0, stream>>>(k);

    attn_k<<<dim3(T_ / 64, B_ * H_), blk, 0, stream>>>(q, k, v, y);

    gemm_nt<<<gg, blk, 0, stream>>>(y, Wp, out, M, DIM_, DIM_);
}

// Round 4
// 1109.486 us; speedup vs baseline: 1.4279x; 1.4279x over previous
//
#include <hip/hip_runtime.h>
#include <math.h>

#define B_   2
#define T_   2048
#define DIM_ 1040
#define H_   16
#define HD_  64
#define HD1_ 65
#define NELEM (B_*T_*DIM_)   // 4,259,840 floats per (b,t,dim) tensor

#define KP_   1056           // K padded to mult of 32 (1040 -> 1056)
#define KPP_  3168           // 3*KP_ : split-triplet K
#define NP_   1152           // weight rows padded to mult of 128
#define SEGS_ 132            // KP_/8

typedef __attribute__((ext_vector_type(8))) __bf16 bf16x8;
typedef __attribute__((ext_vector_type(4))) float f32x4;
typedef __attribute__((ext_vector_type(8))) unsigned short ushort8;

// ---------------------------------------------------------------------------
// Weight fp32 -> split-bf16 triplet (hi, lo, hi).  Paired with activation
// triplets (hi, hi, lo), a plain bf16 dot over K''=3K computes
// hi*hi + hi*lo + lo*hi  (drops only the ~2^-18 lo*lo term).
// out: [NP_][KPP_] bf16, zero-padded rows/cols.
// ---------------------------------------------------------------------------
__global__ __launch_bounds__(256)
void convert_w(const float* __restrict__ in, __bf16* __restrict__ out)
{
    const int gid = blockIdx.x * 256 + threadIdx.x;
    if (gid >= NP_ * SEGS_) return;
    const int r = gid / SEGS_, s = gid - r * SEGS_;

    float v[8];
    if (r < DIM_ && s < 130) {              // 130*8 = 1040 exactly
        const float4 f0 = *(const float4*)(in + (size_t)r * DIM_ + s * 8);
        const float4 f1 = *(const float4*)(in + (size_t)r * DIM_ + s * 8 + 4);
        v[0]=f0.x; v[1]=f0.y; v[2]=f0.z; v[3]=f0.w;
        v[4]=f1.x; v[5]=f1.y; v[6]=f1.z; v[7]=f1.w;
    } else {
        #pragma unroll
        for (int i = 0; i < 8; ++i) v[i] = 0.0f;
    }

    __bf16 t[24] __attribute__((aligned(16)));
    #pragma unroll
    for (int i = 0; i < 8; ++i) {
        const __bf16 hi = (__bf16)v[i];
        const __bf16 lo = (__bf16)(v[i] - (float)hi);
        t[3*i] = hi; t[3*i+1] = lo; t[3*i+2] = hi;
    }

    __bf16* o = out + (size_t)r * KPP_ + s * 24;
    *(ushort8*)(o)      = *(const ushort8*)(t);
    *(ushort8*)(o + 8)  = *(const ushort8*)(t + 8);
    *(ushort8*)(o + 16) = *(const ushort8*)(t + 16);
}

// ---------------------------------------------------------------------------
// Fused-conversion MFMA GEMM:  C[M,1040] = Afp32[M,1040] . Wc[NP_,KPP_]^T
// A is converted to (hi,hi,lo) triplets on the fly while staging into LDS.
// 128x128 tile, 4 waves, 64x64 per wave via 4x4 frags of 16x16x32 bf16.
// K-step = 32 original k = 96 triplet-k = 3 MFMA k-substeps.
// LDS: As[128][96] + Bs[128][96] = 48 KB.
// ---------------------------------------------------------------------------
__device__ __forceinline__ void gload_lds16(const void* g, void* l) {
    __builtin_amdgcn_global_load_lds(
        (const __attribute__((address_space(1))) void*)g,
        (__attribute__((address_space(3))) void*)l, 16, 0, 0);
}

__global__ __launch_bounds__(256)
void gemm_fused(const float* __restrict__ A, const __bf16* __restrict__ Bw,
                float* __restrict__ C)
{
    __shared__ __bf16 As[128 * 96];
    __shared__ __bf16 Bs[128 * 96];

    const int tid  = threadIdx.x;
    const int lane = tid & 63;
    const int w    = tid >> 6;
    const int wr   = (w >> 1) * 64, wc = (w & 1) * 64;
    const int m0   = blockIdx.y * 128, n0 = blockIdx.x * 128;

    // A staging: thread -> row tid>>1, col-group (tid&1)*16 (16 fp32 -> 48 bf16)
    const int ar  = tid >> 1, acg = (tid & 1) * 16;
    const float* ga = A + (size_t)(m0 + ar) * DIM_ + acg;
    __bf16* la = As + ar * 96 + acg * 3;

    // B staging: 6 x (8 bf16/thread) via global_load_lds, LDS linear in lane
    // order: chunk cid = bb*256+tid -> Bs elem cid*8 == row cid/12, col (cid%12)*8
    const __bf16* gb[6];
    #pragma unroll
    for (int bb = 0; bb < 6; ++bb) {
        const int cid = bb * 256 + tid;
        const int br  = cid / 12, bc = cid - br * 12;
        gb[bb] = Bw + (size_t)(n0 + br) * KPP_ + bc * 8;
    }
    __bf16* lb = Bs + tid * 8;

    f32x4 acc[4][4];
    #pragma unroll
    for (int i = 0; i < 4; ++i)
        #pragma unroll
        for (int j = 0; j < 4; ++j) acc[i][j] = (f32x4){0.f, 0.f, 0.f, 0.f};

    // fragment read base: lane l -> row (l&15), k-offset (l>>4)*8
    const __bf16* pa = As + (wr + (lane & 15)) * 96 + (lane >> 4) * 8;
    const __bf16* pb = Bs + (wc + (lane & 15)) * 96 + (lane >> 4) * 8;

    for (int k0 = 0; k0 < DIM_; k0 += 32) {     // 33 steps (last is half-wide)
        float vv[16];
        if (k0 + acg < DIM_) {                  // 1024+16 <= 1040 always holds
            const float4 f0 = *(const float4*)(ga + k0);
            const float4 f1 = *(const float4*)(ga + k0 + 4);
            const float4 f2 = *(const float4*)(ga + k0 + 8);
            const float4 f3 = *(const float4*)(ga + k0 + 12);
            vv[0]=f0.x;  vv[1]=f0.y;  vv[2]=f0.z;  vv[3]=f0.w;
            vv[4]=f1.x;  vv[5]=f1.y;  vv[6]=f1.z;  vv[7]=f1.w;
            vv[8]=f2.x;  vv[9]=f2.y;  vv[10]=f2.z; vv[11]=f2.w;
            vv[12]=f3.x; vv[13]=f3.y; vv[14]=f3.z; vv[15]=f3.w;
        } else {
            #pragma unroll
            for (int i = 0; i < 16; ++i) vv[i] = 0.0f;
        }

        __syncthreads();                        // prev MFMA done reading LDS

        __bf16 tr[48] __attribute__((aligned(16)));
        #pragma unroll
        for (int i = 0; i < 16; ++i) {
            const __bf16 hi = (__bf16)vv[i];
            const __bf16 lo = (__bf16)(vv[i] - (float)hi);
            tr[3*i] = hi; tr[3*i+1] = hi; tr[3*i+2] = lo;
        }
        #pragma unroll
        for (int s = 0; s < 6; ++s)
            *(ushort8*)(la + s * 8) = *(const ushort8*)(tr + s * 8);

        #pragma unroll
        for (int bb = 0; bb < 6; ++bb)
            gload_lds16(gb[bb] + k0 * 3, lb + bb * 2048);

        __syncthreads();                        // staged (vmcnt+lgkm drained)

        #pragma unroll
        for (int ks = 0; ks < 3; ++ks) {
            bf16x8 a[4], b[4];
            #pragma unroll
            for (int i = 0; i < 4; ++i)
                a[i] = *(const bf16x8*)(pa + i * 16 * 96 + ks * 32);
            #pragma unroll
            for (int j = 0; j < 4; ++j)
                b[j] = *(const bf16x8*)(pb + j * 16 * 96 + ks * 32);
            #pragma unroll
            for (int i = 0; i < 4; ++i)
                #pragma unroll
                for (int j = 0; j < 4; ++j)
                    acc[i][j] = __builtin_amdgcn_mfma_f32_16x16x32_bf16(
                        a[i], b[j], acc[i][j], 0, 0, 0);
        }
    }

    // C/D layout: row = (lane>>4)*4 + reg, col = lane&15   [m89-verified]
    const int rbase = m0 + wr + (lane >> 4) * 4;
    const int cbase = n0 + wc + (lane & 15);
    #pragma unroll
    for (int i = 0; i < 4; ++i)
        #pragma unroll
        for (int j = 0; j < 4; ++j) {
            const int n = cbase + j * 16;
            if (n < DIM_) {
                #pragma unroll
                for (int r = 0; r < 4; ++r)
                    C[(size_t)(rbase + i * 16 + r) * DIM_ + n] = acc[i][j][r];
            }
        }
}

// ---------------------------------------------------------------------------
// Hyperbolic rotary, in-place on q or k buffer of shape (B,T,H,HD1).
// One wave (64 lanes) per (b,t,h) vector. x0 is recomputed; original x0 unused.
// ---------------------------------------------------------------------------
__global__ __launch_bounds__(256)
void rotary_k(float* __restrict__ X)
{
    const int wid  = (blockIdx.x * 256 + threadIdx.x) >> 6;  // global wave id
    const int lane = threadIdx.x & 63;
    if (wid >= B_ * T_ * H_) return;

    const int h  = wid & (H_ - 1);
    const int bt = wid >> 4;          // b*T + t
    const int t  = bt & (T_ - 1);
    float* base = X + (size_t)bt * DIM_ + h * HD1_;

    const int j = lane & 31;
    // ref: inv_freq = 1/10000^(2j/(HD-2eps));  (HD-2eps) rounds to 64.0 in fp32
    const float pw   = powf(10000.0f, (float)j * (1.0f / 32.0f));
    const float invf = 1.0f / pw;
    const float fr   = (float)t * invf;   // fp32 outer product, same as ref
    const float cs   = cosf(fr);
    const float sn   = sinf(fr);

    const float x1 = base[1 + j];
    const float x2 = base[33 + j];

    float rot = (lane < 32) ? (x1 * cs + x2 * sn)     // y1
                            : (x2 * cs - x1 * sn);    // y2
    rot = fminf(fmaxf(rot, -1000.0f), 1000.0f);

    float sq = rot * rot;
    #pragma unroll
    for (int off = 32; off >= 1; off >>= 1)
        sq += __shfl_xor(sq, off, 64);
    sq = fminf(fmaxf(sq, 0.0f), 1.0e6f);

    const float x0 = sqrtf((1.0f + sq) + 1.0e-6f);

    base[1 + lane] = rot;
    if (lane == 0) base[0] = x0;
}

// ---------------------------------------------------------------------------
// Attention: per block = one (b,h) and 64 q rows; stream K/V in 64-wide tiles.
// logits = (q_sp.k_sp - q0*k0)/8 clipped +-100 (sign folded: qtT[0] = -q0),
// full (non-causal) online softmax, acc = sum p*v, normalized at the end.
// ---------------------------------------------------------------------------
__global__ __launch_bounds__(256)
void attn_k(const float* __restrict__ Q, const float* __restrict__ K,
            const float* __restrict__ V, float* __restrict__ Y)
{
    __shared__ float qtT[HD1_][68];   // [c][r]
    __shared__ float kv [HD1_][68];   // K phase: [c][s]; V phase: [s][c]
    __shared__ float st [64][68];     // scores then exp(scores)
    __shared__ float mrow[64], lrow[64], arow[64];

    const int tid = threadIdx.x;
    const int tx  = tid & 15, ty = tid >> 4;
    const int bh  = blockIdx.y;            // b*H + h
    const int b   = bh >> 4, h = bh & 15;
    const int q0r = blockIdx.x * 64;
    const size_t hb = (size_t)b * T_ * DIM_ + (size_t)h * HD1_;

    for (int idx = tid; idx < 64 * HD1_; idx += 256) {
        const int r = idx / HD1_, c = idx - r * HD1_;
        const float val = Q[hb + (size_t)(q0r + r) * DIM_ + c];
        qtT[c][r] = (c == 0) ? -val : val;   // fold Lorentz sign
    }
    if (tid < 64) { mrow[tid] = -1.0e30f; lrow[tid] = 0.0f; }

    float acc[4][5] = {};   // rows ty+16i, dims tx+16j (j==4 valid only tx==0)

    for (int s0 = 0; s0 < T_; s0 += 64) {
        __syncthreads();   // prev PV done reading kv/st (and q-load on iter 0)

        // ---- stage K tile transposed: kv[c][s] ----
        for (int idx = tid; idx < 64 * HD1_; idx += 256) {
            const int r = idx / HD1_, c = idx - r * HD1_;
            kv[c][r] = K[hb + (size_t)(s0 + r) * DIM_ + c];
        }
        __syncthreads();   // K ready

        // ---- scores: rows ty+16i, cols tx*4+jj ----
        float sc[4][4] = {};
        for (int kk = 0; kk < HD1_; ++kk) {
            float a[4];
            #pragma unroll
            for (int i = 0; i < 4; ++i) a[i] = qtT[kk][ty + 16*i];
            const float4 b4 = *(const float4*)&kv[kk][tx * 4];
            #pragma unroll
            for (int i = 0; i < 4; ++i) {
                sc[i][0] += a[i] * b4.x;
                sc[i][1] += a[i] * b4.y;
                sc[i][2] += a[i] * b4.z;
                sc[i][3] += a[i] * b4.w;
            }
        }
        #pragma unroll
        for (int i = 0; i < 4; ++i) {
            float4 o;
            o.x = fminf(fmaxf(sc[i][0] * 0.125f, -100.0f), 100.0f);
            o.y = fminf(fmaxf(sc[i][1] * 0.125f, -100.0f), 100.0f);
            o.z = fminf(fmaxf(sc[i][2] * 0.125f, -100.0f), 100.0f);
            o.w = fminf(fmaxf(sc[i][3] * 0.125f, -100.0f), 100.0f);
            *(float4*)&st[ty + 16*i][tx * 4] = o;
        }
        __syncthreads();   // scores ready; kv free for V

        // ---- online softmax row stats (4 threads per row) ----
        {
            const int rr = tid >> 2, qq = tid & 3;
            float mx = -1.0e30f;
            #pragma unroll
            for (int c = 0; c < 16; ++c) mx = fmaxf(mx, st[rr][qq*16 + c]);
            mx = fmaxf(mx, __shfl_xor(mx, 1, 64));
            mx = fmaxf(mx, __shfl_xor(mx, 2, 64));
            const float mold = mrow[rr];
            const float mnew = fmaxf(mold, mx);
            float sum = 0.0f;
            #pragma unroll
            for (int c = 0; c < 16; ++c) {
                const float p = expf(st[rr][qq*16 + c] - mnew);
                st[rr][qq*16 + c] = p;
                sum += p;
            }
            sum += __shfl_xor(sum, 1, 64);
            sum += __shfl_xor(sum, 2, 64);
            if (qq == 0) {
                const float al = expf(mold - mnew);
                arow[rr] = al;
                mrow[rr] = mnew;
                lrow[rr] = lrow[rr] * al + sum;
            }
        }

        // ---- stage V tile row-major into kv: kv[s][c] ----
        for (int idx = tid; idx < 64 * HD1_; idx += 256) {
            const int r = idx / HD1_, c = idx - r * HD1_;
            kv[r][c] = V[hb + (size_t)(s0 + r) * DIM_ + c];
        }
        __syncthreads();   // exp(st), stats, V all ready

        // ---- PV accumulate ----
        {
            float al[4];
            #pragma unroll
            for (int i = 0; i < 4; ++i) al[i] = arow[ty + 16*i];
            #pragma unroll
            for (int i = 0; i < 4; ++i)
                #pragma unroll
                for (int j = 0; j < 5; ++j) acc[i][j] *= al[i];

            for (int kk = 0; kk < 64; ++kk) {
                float p[4];
                #pragma unroll
                for (int i = 0; i < 4; ++i) p[i] = st[ty + 16*i][kk];
                const float v0 = kv[kk][tx];
                const float v1 = kv[kk][tx + 16];
                const float v2 = kv[kk][tx + 32];
                const float v3 = kv[kk][tx + 48];
                const float v4 = kv[kk][64];
                #pragma unroll
                for (int i = 0; i < 4; ++i) {
                    acc[i][0] += p[i] * v0;
                    acc[i][1] += p[i] * v1;
                    acc[i][2] += p[i] * v2;
                    acc[i][3] += p[i] * v3;
                    acc[i][4] += p[i] * v4;
                }
            }
        }
    }

    #pragma unroll
    for (int i = 0; i < 4; ++i) {
        const int r = ty + 16*i;
        const float li = lrow[r];
        const size_t rowb = hb + (size_t)(q0r + r) * DIM_;
        #pragma unroll
        for (int j = 0; j < 5; ++j) {
            const int d = tx + 16*j;
            if (d < HD1_) Y[rowb + d] = acc[i][j] / li;
        }
    }
}

// ---------------------------------------------------------------------------
// Workspace (58.4 MB total, < round-1-proven 68.2 MB):
//   q [NELEM] f32 | k [NELEM] f32 | y [NELEM] f32 | Wc [NP_*KPP_] bf16
// v lives in d_out (dead before the final GEMM overwrites it).
// ---------------------------------------------------------------------------
extern "C" void kernel_launch(void* const* d_in, const int* in_sizes, int n_in,
                              void* d_out, int out_size, void* d_ws, size_t ws_size,
                              hipStream_t stream)
{
    const float* x  = (const float*)d_in[0];
    const float* Wq = (const float*)d_in[1];
    const float* Wk = (const float*)d_in[2];
    const float* Wv = (const float*)d_in[3];
    const float* Wp = (const float*)d_in[4];

    float* q = (float*)d_ws;
    float* k = q + NELEM;
    float* y = k + NELEM;
    __bf16* Wc = (__bf16*)(y + NELEM);     // [NP_][KPP_] = 7.3 MB
    float* out = (float*)d_out;
    float* v   = out;                      // v parked in d_out

    const int M = B_ * T_;                 // 4096
    dim3 blk(256);
    dim3 gcw((NP_ * SEGS_ + 255) / 256);   // weight convert: 594 blocks
    dim3 gg(NP_ / 128, M / 128);           // (9, 32)

    convert_w<<<gcw, blk, 0, stream>>>(Wq, Wc);
    gemm_fused<<<gg, blk, 0, stream>>>(x, Wc, q);
    convert_w<<<gcw, blk, 0, stream>>>(Wk, Wc);
    gemm_fused<<<gg, blk, 0, stream>>>(x, Wc, k);
    convert_w<<<gcw, blk, 0, stream>>>(Wv, Wc);
    gemm_fused<<<gg, blk, 0, stream>>>(x, Wc, v);

    rotary_k<<<(B_ * T_ * H_) / 4, blk, 0, stream>>>(q);
    rotary_k<<<(B_ * T_ * H_) / 4, blk, 0, stream>>>(k);

    attn_k<<<dim3(T_ / 64, B_ * H_), blk, 0, stream>>>(q, k, v, y);

    convert_w<<<gcw, blk, 0, stream>>>(Wp, Wc);
    gemm_fused<<<gg, blk, 0, stream>>>(y, Wc, out);
}

// Round 5
// 799.550 us; speedup vs baseline: 1.9814x; 1.3876x over previous
//
#include <hip/hip_runtime.h>
#include <math.h>

#define B_   2
#define T_   2048
#define DIM_ 1040
#define H_   16
#define HD_  64
#define HD1_ 65
#define NELEM (B_*T_*DIM_)   // 4,259,840 floats per (b,t,dim) tensor

#define KP_   1056           // K padded to mult of 32 (1040 -> 1056)
#define KPP_  3168           // 3*KP_ : split-triplet K
#define NP_   1152           // weight rows padded to mult of 128
#define SEGS_ 132            // KP_/8

typedef __attribute__((ext_vector_type(8))) __bf16 bf16x8;
typedef __attribute__((ext_vector_type(4))) float f32x4;
typedef __attribute__((ext_vector_type(8))) unsigned short ushort8;

static __device__ __forceinline__ unsigned pack_bf16(float lo, float hi) {
    __bf16 a = (__bf16)lo, c = (__bf16)hi;
    unsigned short ua, uc;
    __builtin_memcpy(&ua, &a, 2);
    __builtin_memcpy(&uc, &c, 2);
    return ((unsigned)uc << 16) | ua;
}

// ---------------------------------------------------------------------------
// Weight fp32 -> split-bf16 triplet (hi, lo, hi).  Paired with activation
// triplets (hi, hi, lo), a plain bf16 dot over K''=3K computes
// hi*hi + hi*lo + lo*hi  (drops only the ~2^-18 lo*lo term).
// ---------------------------------------------------------------------------
__global__ __launch_bounds__(256)
void convert_w(const float* __restrict__ in, __bf16* __restrict__ out)
{
    const int gid = blockIdx.x * 256 + threadIdx.x;
    if (gid >= NP_ * SEGS_) return;
    const int r = gid / SEGS_, s = gid - r * SEGS_;

    float v[8];
    if (r < DIM_ && s < 130) {              // 130*8 = 1040 exactly
        const float4 f0 = *(const float4*)(in + (size_t)r * DIM_ + s * 8);
        const float4 f1 = *(const float4*)(in + (size_t)r * DIM_ + s * 8 + 4);
        v[0]=f0.x; v[1]=f0.y; v[2]=f0.z; v[3]=f0.w;
        v[4]=f1.x; v[5]=f1.y; v[6]=f1.z; v[7]=f1.w;
    } else {
        #pragma unroll
        for (int i = 0; i < 8; ++i) v[i] = 0.0f;
    }

    __bf16 t[24] __attribute__((aligned(16)));
    #pragma unroll
    for (int i = 0; i < 8; ++i) {
        const __bf16 hi = (__bf16)v[i];
        const __bf16 lo = (__bf16)(v[i] - (float)hi);
        t[3*i] = hi; t[3*i+1] = lo; t[3*i+2] = hi;
    }

    __bf16* o = out + (size_t)r * KPP_ + s * 24;
    *(ushort8*)(o)      = *(const ushort8*)(t);
    *(ushort8*)(o + 8)  = *(const ushort8*)(t + 8);
    *(ushort8*)(o + 16) = *(const ushort8*)(t + 16);
}

// ---------------------------------------------------------------------------
// Fused-conversion MFMA GEMM:  C[M,1040] = Afp32[M,1040] . Wc[NP_,KPP_]^T
// ---------------------------------------------------------------------------
__device__ __forceinline__ void gload_lds16(const void* g, void* l) {
    __builtin_amdgcn_global_load_lds(
        (const __attribute__((address_space(1))) void*)g,
        (__attribute__((address_space(3))) void*)l, 16, 0, 0);
}

__global__ __launch_bounds__(256)
void gemm_fused(const float* __restrict__ A, const __bf16* __restrict__ Bw,
                float* __restrict__ C)
{
    __shared__ __bf16 As[128 * 96];
    __shared__ __bf16 Bs[128 * 96];

    const int tid  = threadIdx.x;
    const int lane = tid & 63;
    const int w    = tid >> 6;
    const int wr   = (w >> 1) * 64, wc = (w & 1) * 64;
    const int m0   = blockIdx.y * 128, n0 = blockIdx.x * 128;

    const int ar  = tid >> 1, acg = (tid & 1) * 16;
    const float* ga = A + (size_t)(m0 + ar) * DIM_ + acg;
    __bf16* la = As + ar * 96 + acg * 3;

    const __bf16* gb[6];
    #pragma unroll
    for (int bb = 0; bb < 6; ++bb) {
        const int cid = bb * 256 + tid;
        const int br  = cid / 12, bc = cid - br * 12;
        gb[bb] = Bw + (size_t)(n0 + br) * KPP_ + bc * 8;
    }
    __bf16* lb = Bs + tid * 8;

    f32x4 acc[4][4];
    #pragma unroll
    for (int i = 0; i < 4; ++i)
        #pragma unroll
        for (int j = 0; j < 4; ++j) acc[i][j] = (f32x4){0.f, 0.f, 0.f, 0.f};

    const __bf16* pa = As + (wr + (lane & 15)) * 96 + (lane >> 4) * 8;
    const __bf16* pb = Bs + (wc + (lane & 15)) * 96 + (lane >> 4) * 8;

    for (int k0 = 0; k0 < DIM_; k0 += 32) {
        float vv[16];
        if (k0 + acg < DIM_) {
            const float4 f0 = *(const float4*)(ga + k0);
            const float4 f1 = *(const float4*)(ga + k0 + 4);
            const float4 f2 = *(const float4*)(ga + k0 + 8);
            const float4 f3 = *(const float4*)(ga + k0 + 12);
            vv[0]=f0.x;  vv[1]=f0.y;  vv[2]=f0.z;  vv[3]=f0.w;
            vv[4]=f1.x;  vv[5]=f1.y;  vv[6]=f1.z;  vv[7]=f1.w;
            vv[8]=f2.x;  vv[9]=f2.y;  vv[10]=f2.z; vv[11]=f2.w;
            vv[12]=f3.x; vv[13]=f3.y; vv[14]=f3.z; vv[15]=f3.w;
        } else {
            #pragma unroll
            for (int i = 0; i < 16; ++i) vv[i] = 0.0f;
        }

        __syncthreads();

        __bf16 tr[48] __attribute__((aligned(16)));
        #pragma unroll
        for (int i = 0; i < 16; ++i) {
            const __bf16 hi = (__bf16)vv[i];
            const __bf16 lo = (__bf16)(vv[i] - (float)hi);
            tr[3*i] = hi; tr[3*i+1] = hi; tr[3*i+2] = lo;
        }
        #pragma unroll
        for (int s = 0; s < 6; ++s)
            *(ushort8*)(la + s * 8) = *(const ushort8*)(tr + s * 8);

        #pragma unroll
        for (int bb = 0; bb < 6; ++bb)
            gload_lds16(gb[bb] + k0 * 3, lb + bb * 2048);

        __syncthreads();

        #pragma unroll
        for (int ks = 0; ks < 3; ++ks) {
            bf16x8 a[4], b[4];
            #pragma unroll
            for (int i = 0; i < 4; ++i)
                a[i] = *(const bf16x8*)(pa + i * 16 * 96 + ks * 32);
            #pragma unroll
            for (int j = 0; j < 4; ++j)
                b[j] = *(const bf16x8*)(pb + j * 16 * 96 + ks * 32);
            #pragma unroll
            for (int i = 0; i < 4; ++i)
                #pragma unroll
                for (int j = 0; j < 4; ++j)
                    acc[i][j] = __builtin_amdgcn_mfma_f32_16x16x32_bf16(
                        a[i], b[j], acc[i][j], 0, 0, 0);
        }
    }

    const int rbase = m0 + wr + (lane >> 4) * 4;
    const int cbase = n0 + wc + (lane & 15);
    #pragma unroll
    for (int i = 0; i < 4; ++i)
        #pragma unroll
        for (int j = 0; j < 4; ++j) {
            const int n = cbase + j * 16;
            if (n < DIM_) {
                #pragma unroll
                for (int r = 0; r < 4; ++r)
                    C[(size_t)(rbase + i * 16 + r) * DIM_ + n] = acc[i][j][r];
            }
        }
}

// ---------------------------------------------------------------------------
// Hyperbolic rotary, in-place on q or k buffer of shape (B,T,H,HD1).
// ---------------------------------------------------------------------------
__global__ __launch_bounds__(256)
void rotary_k(float* __restrict__ X)
{
    const int wid  = (blockIdx.x * 256 + threadIdx.x) >> 6;
    const int lane = threadIdx.x & 63;
    if (wid >= B_ * T_ * H_) return;

    const int h  = wid & (H_ - 1);
    const int bt = wid >> 4;
    const int t  = bt & (T_ - 1);
    float* base = X + (size_t)bt * DIM_ + h * HD1_;

    const int j = lane & 31;
    const float pw   = powf(10000.0f, (float)j * (1.0f / 32.0f));
    const float invf = 1.0f / pw;
    const float fr   = (float)t * invf;
    const float cs   = cosf(fr);
    const float sn   = sinf(fr);

    const float x1 = base[1 + j];
    const float x2 = base[33 + j];

    float rot = (lane < 32) ? (x1 * cs + x2 * sn)
                            : (x2 * cs - x1 * sn);
    rot = fminf(fmaxf(rot, -1000.0f), 1000.0f);

    float sq = rot * rot;
    #pragma unroll
    for (int off = 32; off >= 1; off >>= 1)
        sq += __shfl_xor(sq, off, 64);
    sq = fminf(fmaxf(sq, 0.0f), 1.0e6f);

    const float x0 = sqrtf((1.0f + sq) + 1.0e-6f);

    base[1 + lane] = rot;
    if (lane == 0) base[0] = x0;
}

// ---------------------------------------------------------------------------
// MFMA attention. Block = (b,h) x 64 q-rows; 4 waves x 16 q-rows each.
// QK^T: full 65-dim bf16 MFMA (k padded to 96 w/ zeros in Kt), then per-score
// fp32 Lorentz fix: s = (mfma - q0b*k0b - q0f*k0f)/8, clip +-100.
// Online softmax in registers (per-lane rows). P->bf16->LDS (C-layout),
// re-read as A-operand by the SAME wave (no extra barrier).
// V staged transposed [d][s] so PV B-operand reads are contiguous.
// LDS strides: Qt/Kt 104, VtT/Pt 72 (fragment reads <=2-way conflicts).
// ---------------------------------------------------------------------------
__global__ __launch_bounds__(256)
void attn_mfma(const float* __restrict__ Q, const float* __restrict__ K,
               const float* __restrict__ V, float* __restrict__ Y)
{
    __shared__ __bf16 Qt[64 * 104] __attribute__((aligned(16)));
    __shared__ __bf16 Kt[64 * 104] __attribute__((aligned(16)));
    __shared__ __bf16 VtT[80 * 72] __attribute__((aligned(16)));
    __shared__ __bf16 Pt[64 * 72]  __attribute__((aligned(16)));
    __shared__ float q0f[64], k0f[64];

    const int tid  = threadIdx.x;
    const int lane = tid & 63;
    const int w    = tid >> 6;
    const int lx   = lane & 15;
    const int ly   = lane >> 4;
    const int bh   = blockIdx.y;
    const int b    = bh >> 4, h = bh & 15;
    const int q0r  = blockIdx.x * 64;
    const size_t hb = (size_t)b * T_ * DIM_ + (size_t)h * HD1_;

    // zero-fill Kt once (cols 66..95 must stay zero for the padded k-steps)
    for (int i = tid; i < 64 * 104 / 2; i += 256) ((unsigned*)Kt)[i] = 0u;

    // stage Q tile: Qt[r][0..65] bf16 (col65=0), q0f[r] fp32
    for (int idx = tid; idx < 64 * 33; idx += 256) {
        const int r = idx / 33, j = idx - r * 33;
        const float* src = Q + hb + (size_t)(q0r + r) * DIM_ + 2 * j;
        const float f0 = src[0];
        const float f1 = (j < 32) ? src[1] : 0.0f;
        if (j == 0) q0f[r] = f0;
        *(unsigned*)&Qt[r * 104 + 2 * j] = pack_bf16(f0, f1);
    }

    f32x4 acc_o[5];
    #pragma unroll
    for (int n = 0; n < 5; ++n) acc_o[n] = (f32x4){0.f, 0.f, 0.f, 0.f};
    float m_r[4] = {-1.0e30f, -1.0e30f, -1.0e30f, -1.0e30f};
    float l_r[4] = {0.f, 0.f, 0.f, 0.f};

    for (int s0 = 0; s0 < T_; s0 += 64) {
        __syncthreads();   // prev iter's MFMA reads of Kt/VtT done (iter0: Q staged)

        // ---- stage K tile: Kt[r][0..65], k0f[r] ----
        for (int idx = tid; idx < 64 * 33; idx += 256) {
            const int r = idx / 33, j = idx - r * 33;
            const float* src = K + hb + (size_t)(s0 + r) * DIM_ + 2 * j;
            const float f0 = src[0];
            const float f1 = (j < 32) ? src[1] : 0.0f;
            if (j == 0) k0f[r] = f0;
            *(unsigned*)&Kt[r * 104 + 2 * j] = pack_bf16(f0, f1);
        }
        // ---- stage V transposed: VtT[d][s] = V[s0+s][d] ----
        for (int idx = tid; idx < 64 * 65; idx += 256) {
            const int s = idx / 65, d = idx - s * 65;
            VtT[d * 72 + s] = (__bf16)V[hb + (size_t)(s0 + s) * DIM_ + d];
        }
        __syncthreads();   // K,V staged

        // ---- QK^T: wave w -> q rows w*16..+15, all 64 s cols ----
        bf16x8 aq[3];
        #pragma unroll
        for (int ks = 0; ks < 3; ++ks)
            aq[ks] = *(const bf16x8*)&Qt[(w * 16 + lx) * 104 + ks * 32 + ly * 8];

        f32x4 sc[4];
        #pragma unroll
        for (int n = 0; n < 4; ++n) {
            f32x4 c = (f32x4){0.f, 0.f, 0.f, 0.f};
            #pragma unroll
            for (int ks = 0; ks < 3; ++ks) {
                const bf16x8 bk =
                    *(const bf16x8*)&Kt[(n * 16 + lx) * 104 + ks * 32 + ly * 8];
                c = __builtin_amdgcn_mfma_f32_16x16x32_bf16(aq[ks], bk, c, 0, 0, 0);
            }
            sc[n] = c;
        }

        // ---- scores: fp32 Lorentz fix, scale, clip ----
        float q0v[4], q0b[4], k0v[4], k0b[4];
        #pragma unroll
        for (int r = 0; r < 4; ++r) {
            q0v[r] = q0f[w * 16 + ly * 4 + r];
            q0b[r] = (float)(__bf16)q0v[r];
        }
        #pragma unroll
        for (int n = 0; n < 4; ++n) {
            k0v[n] = k0f[n * 16 + lx];
            k0b[n] = (float)(__bf16)k0v[n];
        }

        float p[4][4];     // [n][r]
        float rmax[4] = {-1.0e30f, -1.0e30f, -1.0e30f, -1.0e30f};
        #pragma unroll
        for (int n = 0; n < 4; ++n)
            #pragma unroll
            for (int r = 0; r < 4; ++r) {
                float s = (sc[n][r] - q0b[r] * k0b[n] - q0v[r] * k0v[n]) * 0.125f;
                s = fminf(fmaxf(s, -100.0f), 100.0f);
                p[n][r] = s;
                rmax[r] = fmaxf(rmax[r], s);
            }
        #pragma unroll
        for (int r = 0; r < 4; ++r) {
            rmax[r] = fmaxf(rmax[r], __shfl_xor(rmax[r], 1, 64));
            rmax[r] = fmaxf(rmax[r], __shfl_xor(rmax[r], 2, 64));
            rmax[r] = fmaxf(rmax[r], __shfl_xor(rmax[r], 4, 64));
            rmax[r] = fmaxf(rmax[r], __shfl_xor(rmax[r], 8, 64));
        }
        float alpha[4], rsum[4];
        #pragma unroll
        for (int r = 0; r < 4; ++r) {
            const float mn = fmaxf(m_r[r], rmax[r]);
            alpha[r] = __expf(m_r[r] - mn);
            m_r[r] = mn;
            rsum[r] = 0.0f;
        }
        #pragma unroll
        for (int n = 0; n < 4; ++n)
            #pragma unroll
            for (int r = 0; r < 4; ++r) {
                p[n][r] = __expf(p[n][r] - m_r[r]);
                rsum[r] += p[n][r];
            }
        #pragma unroll
        for (int r = 0; r < 4; ++r) {
            rsum[r] += __shfl_xor(rsum[r], 1, 64);
            rsum[r] += __shfl_xor(rsum[r], 2, 64);
            rsum[r] += __shfl_xor(rsum[r], 4, 64);
            rsum[r] += __shfl_xor(rsum[r], 8, 64);
            l_r[r] = l_r[r] * alpha[r] + rsum[r];
        }

        // ---- write P (bf16) in C-layout; same wave re-reads as A-operand ----
        #pragma unroll
        for (int n = 0; n < 4; ++n)
            #pragma unroll
            for (int r = 0; r < 4; ++r)
                Pt[(w * 16 + ly * 4 + r) * 72 + n * 16 + lx] = (__bf16)p[n][r];

        // ---- rescale O ----
        #pragma unroll
        for (int n = 0; n < 5; ++n)
            #pragma unroll
            for (int r = 0; r < 4; ++r) acc_o[n][r] *= alpha[r];

        // ---- PV: O[q][d] += P[q][s] * V[s][d] ----
        bf16x8 ap[2];
        #pragma unroll
        for (int ks = 0; ks < 2; ++ks)
            ap[ks] = *(const bf16x8*)&Pt[(w * 16 + lx) * 72 + ks * 32 + ly * 8];
        #pragma unroll
        for (int n = 0; n < 5; ++n) {
            f32x4 c = acc_o[n];
            #pragma unroll
            for (int ks = 0; ks < 2; ++ks) {
                const bf16x8 bv =
                    *(const bf16x8*)&VtT[(n * 16 + lx) * 72 + ks * 32 + ly * 8];
                c = __builtin_amdgcn_mfma_f32_16x16x32_bf16(ap[ks], bv, c, 0, 0, 0);
            }
            acc_o[n] = c;
        }
    }

    // ---- epilogue: normalize and store (d = 0..64) ----
    #pragma unroll
    for (int r = 0; r < 4; ++r) {
        const int qrow = q0r + w * 16 + ly * 4 + r;
        const float inv = 1.0f / l_r[r];
        const size_t rowb = hb + (size_t)qrow * DIM_;
        #pragma unroll
        for (int n = 0; n < 4; ++n)
            Y[rowb + n * 16 + lx] = acc_o[n][r] * inv;
        if (lx == 0) Y[rowb + 64] = acc_o[4][r] * inv;
    }
}

// ---------------------------------------------------------------------------
// Workspace (58.4 MB): q | k | y (f32) + Wc (bf16). v parked in d_out.
// ---------------------------------------------------------------------------
extern "C" void kernel_launch(void* const* d_in, const int* in_sizes, int n_in,
                              void* d_out, int out_size, void* d_ws, size_t ws_size,
                              hipStream_t stream)
{
    const float* x  = (const float*)d_in[0];
    const float* Wq = (const float*)d_in[1];
    const float* Wk = (const float*)d_in[2];
    const float* Wv = (const float*)d_in[3];
    const float* Wp = (const float*)d_in[4];

    float* q = (float*)d_ws;
    float* k = q + NELEM;
    float* y = k + NELEM;
    __bf16* Wc = (__bf16*)(y + NELEM);
    float* out = (float*)d_out;
    float* v   = out;

    const int M = B_ * T_;
    dim3 blk(256);
    dim3 gcw((NP_ * SEGS_ + 255) / 256);
    dim3 gg(NP_ / 128, M / 128);

    convert_w<<<gcw, blk, 0, stream>>>(Wq, Wc);
    gemm_fused<<<gg, blk, 0, stream>>>(x, Wc, q);
    convert_w<<<gcw, blk, 0, stream>>>(Wk, Wc);
    gemm_fused<<<gg, blk, 0, stream>>>(x, Wc, k);
    convert_w<<<gcw, blk, 0, stream>>>(Wv, Wc);
    gemm_fused<<<gg, blk, 0, stream>>>(x, Wc, v);

    rotary_k<<<(B_ * T_ * H_) / 4, blk, 0, stream>>>(q);
    rotary_k<<<(B_ * T_ * H_) / 4, blk, 0, stream>>>(k);

    attn_mfma<<<dim3(T_ / 64, B_ * H_), blk, 0, stream>>>(q, k, v, y);

    convert_w<<<gcw, blk, 0, stream>>>(Wp, Wc);
    gemm_fused<<<gg, blk, 0, stream>>>(y, Wc, out);
}

// Round 6
// 474.870 us; speedup vs baseline: 3.3362x; 1.6837x over previous
//
#include <hip/hip_runtime.h>
#include <math.h>

#define B_   2
#define T_   2048
#define DIM_ 1040
#define H_   16
#define HD_  64
#define HD1_ 65
#define NELEM (B_*T_*DIM_)   // 4,259,840 floats per (b,t,dim) tensor

#define KP_   1056           // K padded to mult of 32 (1040 -> 1056)
#define KPP_  3168           // 3*KP_ : split-triplet K
#define NP_   1152           // weight rows padded to mult of 128
#define SEGS_ 132            // KP_/8

#define NBH_  (B_*H_)        // 32
#define VTR_  72             // VT rows per bh (65 real + 7 zero)

typedef __attribute__((ext_vector_type(8))) __bf16 bf16x8;
typedef __attribute__((ext_vector_type(4))) float f32x4;
typedef __attribute__((ext_vector_type(8))) unsigned short ushort8;

static __device__ __forceinline__ unsigned pack_bf16(float lo, float hi) {
    __bf16 a = (__bf16)lo, c = (__bf16)hi;
    unsigned short ua, uc;
    __builtin_memcpy(&ua, &a, 2);
    __builtin_memcpy(&uc, &c, 2);
    return ((unsigned)uc << 16) | ua;
}

// ---------------------------------------------------------------------------
// Weight fp32 -> split-bf16 triplet (hi, lo, hi).  Paired with activation
// triplets (hi, hi, lo): bf16 dot over K''=3K = hi*hi + hi*lo + lo*hi.
// ---------------------------------------------------------------------------
__global__ __launch_bounds__(256)
void convert_w(const float* __restrict__ in, __bf16* __restrict__ out)
{
    const int gid = blockIdx.x * 256 + threadIdx.x;
    if (gid >= NP_ * SEGS_) return;
    const int r = gid / SEGS_, s = gid - r * SEGS_;

    float v[8];
    if (r < DIM_ && s < 130) {              // 130*8 = 1040 exactly
        const float4 f0 = *(const float4*)(in + (size_t)r * DIM_ + s * 8);
        const float4 f1 = *(const float4*)(in + (size_t)r * DIM_ + s * 8 + 4);
        v[0]=f0.x; v[1]=f0.y; v[2]=f0.z; v[3]=f0.w;
        v[4]=f1.x; v[5]=f1.y; v[6]=f1.z; v[7]=f1.w;
    } else {
        #pragma unroll
        for (int i = 0; i < 8; ++i) v[i] = 0.0f;
    }

    __bf16 t[24] __attribute__((aligned(16)));
    #pragma unroll
    for (int i = 0; i < 8; ++i) {
        const __bf16 hi = (__bf16)v[i];
        const __bf16 lo = (__bf16)(v[i] - (float)hi);
        t[3*i] = hi; t[3*i+1] = lo; t[3*i+2] = hi;
    }

    __bf16* o = out + (size_t)r * KPP_ + s * 24;
    *(ushort8*)(o)      = *(const ushort8*)(t);
    *(ushort8*)(o + 8)  = *(const ushort8*)(t + 8);
    *(ushort8*)(o + 16) = *(const ushort8*)(t + 16);
}

// ---------------------------------------------------------------------------
// Fused-conversion MFMA GEMM:  [M,1040] = Afp32[M,1040] . Wc[NP_,KPP_]^T
// EPI 0: C fp32 row-major.  EPI 1: VT bf16 [bh][d][t]  (per-head transpose).
// ---------------------------------------------------------------------------
__device__ __forceinline__ void gload_lds16(const void* g, void* l) {
    __builtin_amdgcn_global_load_lds(
        (const __attribute__((address_space(1))) void*)g,
        (__attribute__((address_space(3))) void*)l, 16, 0, 0);
}

template<int EPI>
__global__ __launch_bounds__(256)
void gemm_fused(const float* __restrict__ A, const __bf16* __restrict__ Bw,
                float* __restrict__ C, __bf16* __restrict__ VTout)
{
    __shared__ __bf16 As[128 * 96];
    __shared__ __bf16 Bs[128 * 96];

    const int tid  = threadIdx.x;
    const int lane = tid & 63;
    const int w    = tid >> 6;
    const int wr   = (w >> 1) * 64, wc = (w & 1) * 64;
    const int m0   = blockIdx.y * 128, n0 = blockIdx.x * 128;

    const int ar  = tid >> 1, acg = (tid & 1) * 16;
    const float* ga = A + (size_t)(m0 + ar) * DIM_ + acg;
    __bf16* la = As + ar * 96 + acg * 3;

    const __bf16* gb[6];
    #pragma unroll
    for (int bb = 0; bb < 6; ++bb) {
        const int cid = bb * 256 + tid;
        const int br  = cid / 12, bc = cid - br * 12;
        gb[bb] = Bw + (size_t)(n0 + br) * KPP_ + bc * 8;
    }
    __bf16* lb = Bs + tid * 8;

    f32x4 acc[4][4];
    #pragma unroll
    for (int i = 0; i < 4; ++i)
        #pragma unroll
        for (int j = 0; j < 4; ++j) acc[i][j] = (f32x4){0.f, 0.f, 0.f, 0.f};

    const __bf16* pa = As + (wr + (lane & 15)) * 96 + (lane >> 4) * 8;
    const __bf16* pb = Bs + (wc + (lane & 15)) * 96 + (lane >> 4) * 8;

    for (int k0 = 0; k0 < DIM_; k0 += 32) {
        float vv[16];
        if (k0 + acg < DIM_) {
            const float4 f0 = *(const float4*)(ga + k0);
            const float4 f1 = *(const float4*)(ga + k0 + 4);
            const float4 f2 = *(const float4*)(ga + k0 + 8);
            const float4 f3 = *(const float4*)(ga + k0 + 12);
            vv[0]=f0.x;  vv[1]=f0.y;  vv[2]=f0.z;  vv[3]=f0.w;
            vv[4]=f1.x;  vv[5]=f1.y;  vv[6]=f1.z;  vv[7]=f1.w;
            vv[8]=f2.x;  vv[9]=f2.y;  vv[10]=f2.z; vv[11]=f2.w;
            vv[12]=f3.x; vv[13]=f3.y; vv[14]=f3.z; vv[15]=f3.w;
        } else {
            #pragma unroll
            for (int i = 0; i < 16; ++i) vv[i] = 0.0f;
        }

        __syncthreads();

        __bf16 tr[48] __attribute__((aligned(16)));
        #pragma unroll
        for (int i = 0; i < 16; ++i) {
            const __bf16 hi = (__bf16)vv[i];
            const __bf16 lo = (__bf16)(vv[i] - (float)hi);
            tr[3*i] = hi; tr[3*i+1] = hi; tr[3*i+2] = lo;
        }
        #pragma unroll
        for (int s = 0; s < 6; ++s)
            *(ushort8*)(la + s * 8) = *(const ushort8*)(tr + s * 8);

        #pragma unroll
        for (int bb = 0; bb < 6; ++bb)
            gload_lds16(gb[bb] + k0 * 3, lb + bb * 2048);

        __syncthreads();

        #pragma unroll
        for (int ks = 0; ks < 3; ++ks) {
            bf16x8 a[4], b[4];
            #pragma unroll
            for (int i = 0; i < 4; ++i)
                a[i] = *(const bf16x8*)(pa + i * 16 * 96 + ks * 32);
            #pragma unroll
            for (int j = 0; j < 4; ++j)
                b[j] = *(const bf16x8*)(pb + j * 16 * 96 + ks * 32);
            #pragma unroll
            for (int i = 0; i < 4; ++i)
                #pragma unroll
                for (int j = 0; j < 4; ++j)
                    acc[i][j] = __builtin_amdgcn_mfma_f32_16x16x32_bf16(
                        a[i], b[j], acc[i][j], 0, 0, 0);
        }
    }

    // C/D layout: row = (lane>>4)*4 + reg, col = lane&15
    const int rbase = m0 + wr + (lane >> 4) * 4;
    const int cbase = n0 + wc + (lane & 15);
    #pragma unroll
    for (int i = 0; i < 4; ++i) {
        #pragma unroll
        for (int j = 0; j < 4; ++j) {
            const int n = cbase + j * 16;
            if (n < DIM_) {
                if constexpr (EPI == 0) {
                    #pragma unroll
                    for (int r = 0; r < 4; ++r)
                        C[(size_t)(rbase + i * 16 + r) * DIM_ + n] = acc[i][j][r];
                } else {
                    // VT[bh][d][t] = bf16(v[b][t][h*65+d]); 4 consecutive t.
                    const int tg = rbase + i * 16;           // mult of 4
                    const int bb = tg >> 11, tt = tg & (T_ - 1);
                    const int h  = n / 65, d = n - h * 65;
                    const size_t off =
                        ((size_t)(bb * H_ + h) * VTR_ + d) * T_ + tt;
                    uint2 pk;
                    pk.x = pack_bf16(acc[i][j][0], acc[i][j][1]);
                    pk.y = pack_bf16(acc[i][j][2], acc[i][j][3]);
                    *(uint2*)(VTout + off) = pk;
                }
            }
        }
    }
}

// ---------------------------------------------------------------------------
// Rotary + convert: reads GEMM q/k fp32, writes XB bf16 [bh][t][64] (spatial
// only) and X0 fp32 [bh][t] (recomputed time component). No fp32 write-back.
// One wave per (b,t,h).
// ---------------------------------------------------------------------------
__global__ __launch_bounds__(256)
void rotary_conv(const float* __restrict__ X, __bf16* __restrict__ XB,
                 float* __restrict__ X0)
{
    const int wid  = (blockIdx.x * 256 + threadIdx.x) >> 6;
    const int lane = threadIdx.x & 63;
    if (wid >= B_ * T_ * H_) return;

    const int h  = wid & (H_ - 1);
    const int bt = wid >> 4;           // b*T + t
    const int t  = bt & (T_ - 1);
    const int b  = bt >> 11;
    const float* base = X + (size_t)bt * DIM_ + h * HD1_;

    const int j = lane & 31;
    // ref: inv_freq = 1/10000^(2j/(HD-2eps)); (HD-2eps) rounds to 64.0 in fp32
    const float pw   = powf(10000.0f, (float)j * (1.0f / 32.0f));
    const float fr   = (float)t * (1.0f / pw);
    const float cs   = cosf(fr);
    const float sn   = sinf(fr);

    const float x1 = base[1 + j];
    const float x2 = base[33 + j];

    float rot = (lane < 32) ? (x1 * cs + x2 * sn)
                            : (x2 * cs - x1 * sn);
    rot = fminf(fmaxf(rot, -1000.0f), 1000.0f);

    float sq = rot * rot;
    #pragma unroll
    for (int off = 32; off >= 1; off >>= 1)
        sq += __shfl_xor(sq, off, 64);
    sq = fminf(fmaxf(sq, 0.0f), 1.0e6f);

    const float x0 = sqrtf((1.0f + sq) + 1.0e-6f);

    const size_t bht = (size_t)(b * H_ + h) * T_ + t;
    XB[bht * 64 + lane] = (__bf16)rot;
    if (lane == 0) X0[bht] = x0;
}

// ---------------------------------------------------------------------------
// MFMA attention v2.  Block = (bh, 64 q rows); 4 waves x 16 q rows.
// All operands pre-converted bf16; staging = pure global_load_lds width-16
// with XOR-swizzled per-lane SOURCE addresses (linear LDS dest, swizzled
// read: slot' = slot ^ (row&7), rows of 64 bf16 = 128 B).
// logits = (spatial_mfma - q0*k0_fp32)/8, clip +-100; online softmax in regs;
// P bf16 -> LDS (C-layout, stride 72) -> same-wave A-operand re-read.
// ---------------------------------------------------------------------------
__global__ __launch_bounds__(256)
void attn_mfma2(const __bf16* __restrict__ QB, const __bf16* __restrict__ KB,
                const __bf16* __restrict__ VT, const float* __restrict__ Q0,
                const float* __restrict__ K0, float* __restrict__ Y)
{
    __shared__ __bf16 Qt[64 * 64] __attribute__((aligned(16)));
    __shared__ __bf16 Kt[64 * 64] __attribute__((aligned(16)));
    __shared__ __bf16 Vt[80 * 64] __attribute__((aligned(16)));
    __shared__ __bf16 Pt[64 * 72] __attribute__((aligned(16)));
    __shared__ float q0s[64], k0s[64];

    const int tid  = threadIdx.x;
    const int lane = tid & 63;
    const int w    = tid >> 6;
    const int lx   = lane & 15;
    const int ly   = lane >> 4;
    const int bh   = blockIdx.y;
    const int q0r  = blockIdx.x * 64;

    const __bf16* QBb = QB + (size_t)bh * T_ * 64;
    const __bf16* KBb = KB + (size_t)bh * T_ * 64;
    const __bf16* VTb = VT + (size_t)bh * VTR_ * T_;

    // ---- one-time: Q tile staging (swizzled source), Vt zero rows, q0s ----
    #pragma unroll
    for (int qi = 0; qi < 2; ++qi) {
        const int cid = qi * 256 + tid;
        const int r = cid >> 3, j = cid & 7;
        gload_lds16(QBb + (size_t)(q0r + r) * 64 + (j ^ (r & 7)) * 8,
                    Qt + cid * 8);
    }
    ((unsigned*)Vt)[2304 + tid] = 0u;      // rows 72..79 (256 dwords)
    if (tid < 64) q0s[tid] = Q0[(size_t)bh * T_ + q0r + tid];

    // hoisted staging addresses for K (512 chunks) and V (576 chunks)
    const __bf16* gk[2]; __bf16* lk[2];
    #pragma unroll
    for (int qi = 0; qi < 2; ++qi) {
        const int cid = qi * 256 + tid;
        const int r = cid >> 3, j = cid & 7;
        gk[qi] = KBb + r * 64 + (j ^ (r & 7)) * 8;
        lk[qi] = Kt + cid * 8;
    }
    const __bf16* gv[3]; __bf16* lv[3];
    #pragma unroll
    for (int qi = 0; qi < 3; ++qi) {
        const int cid = qi * 256 + tid;
        const int d = cid >> 3, j = cid & 7;
        gv[qi] = VTb + (size_t)(d < VTR_ ? d : 0) * T_ + (j ^ (d & 7)) * 8;
        lv[qi] = Vt + cid * 8;
    }

    f32x4 acc_o[5];
    #pragma unroll
    for (int n = 0; n < 5; ++n) acc_o[n] = (f32x4){0.f, 0.f, 0.f, 0.f};
    float m_r[4] = {-1.0e30f, -1.0e30f, -1.0e30f, -1.0e30f};
    float l_r[4] = {0.f, 0.f, 0.f, 0.f};

    for (int s0 = 0; s0 < T_; s0 += 64) {
        __syncthreads();   // prev compute done with Kt/Vt/k0s (iter0: init done)

        gload_lds16(gk[0] + (size_t)s0 * 64, lk[0]);
        gload_lds16(gk[1] + (size_t)s0 * 64, lk[1]);
        gload_lds16(gv[0] + s0, lv[0]);
        gload_lds16(gv[1] + s0, lv[1]);
        if (tid < 64) {                     // wave-uniform (wave 0 only)
            gload_lds16(gv[2] + s0, lv[2]);
            k0s[tid] = K0[(size_t)bh * T_ + s0 + tid];
        }
        __syncthreads();   // staged

        // ---- QK^T (spatial, 64 dims = 2 k-steps) ----
        bf16x8 aq[2];
        #pragma unroll
        for (int ks = 0; ks < 2; ++ks)
            aq[ks] = *(const bf16x8*)
                &Qt[(w * 16 + lx) * 64 + ((ks * 4 + ly) ^ (lx & 7)) * 8];

        f32x4 sc[4];
        #pragma unroll
        for (int n = 0; n < 4; ++n) {
            f32x4 c = (f32x4){0.f, 0.f, 0.f, 0.f};
            #pragma unroll
            for (int ks = 0; ks < 2; ++ks) {
                const bf16x8 bk = *(const bf16x8*)
                    &Kt[(n * 16 + lx) * 64 + ((ks * 4 + ly) ^ (lx & 7)) * 8];
                c = __builtin_amdgcn_mfma_f32_16x16x32_bf16(aq[ks], bk, c, 0, 0, 0);
            }
            sc[n] = c;
        }

        // ---- scores: fp32 Lorentz fix, scale, clip ----
        float q0v[4], k0v[4];
        #pragma unroll
        for (int r = 0; r < 4; ++r) q0v[r] = q0s[w * 16 + ly * 4 + r];
        #pragma unroll
        for (int n = 0; n < 4; ++n) k0v[n] = k0s[n * 16 + lx];

        float p[4][4];     // [n][r]
        float rmax[4] = {-1.0e30f, -1.0e30f, -1.0e30f, -1.0e30f};
        #pragma unroll
        for (int n = 0; n < 4; ++n)
            #pragma unroll
            for (int r = 0; r < 4; ++r) {
                float s = (sc[n][r] - q0v[r] * k0v[n]) * 0.125f;
                s = fminf(fmaxf(s, -100.0f), 100.0f);
                p[n][r] = s;
                rmax[r] = fmaxf(rmax[r], s);
            }
        #pragma unroll
        for (int r = 0; r < 4; ++r) {
            rmax[r] = fmaxf(rmax[r], __shfl_xor(rmax[r], 1, 64));
            rmax[r] = fmaxf(rmax[r], __shfl_xor(rmax[r], 2, 64));
            rmax[r] = fmaxf(rmax[r], __shfl_xor(rmax[r], 4, 64));
            rmax[r] = fmaxf(rmax[r], __shfl_xor(rmax[r], 8, 64));
        }
        float alpha[4], rsum[4];
        #pragma unroll
        for (int r = 0; r < 4; ++r) {
            const float mn = fmaxf(m_r[r], rmax[r]);
            alpha[r] = __expf(m_r[r] - mn);
            m_r[r] = mn;
            rsum[r] = 0.0f;
        }
        #pragma unroll
        for (int n = 0; n < 4; ++n)
            #pragma unroll
            for (int r = 0; r < 4; ++r) {
                p[n][r] = __expf(p[n][r] - m_r[r]);
                rsum[r] += p[n][r];
            }
        #pragma unroll
        for (int r = 0; r < 4; ++r) {
            rsum[r] += __shfl_xor(rsum[r], 1, 64);
            rsum[r] += __shfl_xor(rsum[r], 2, 64);
            rsum[r] += __shfl_xor(rsum[r], 4, 64);
            rsum[r] += __shfl_xor(rsum[r], 8, 64);
            l_r[r] = l_r[r] * alpha[r] + rsum[r];
        }

        // ---- P (bf16) -> LDS C-layout; same wave re-reads as A-operand ----
        #pragma unroll
        for (int n = 0; n < 4; ++n)
            #pragma unroll
            for (int r = 0; r < 4; ++r)
                Pt[(w * 16 + ly * 4 + r) * 72 + n * 16 + lx] = (__bf16)p[n][r];

        // ---- rescale O ----
        #pragma unroll
        for (int n = 0; n < 5; ++n)
            #pragma unroll
            for (int r = 0; r < 4; ++r) acc_o[n][r] *= alpha[r];

        // ---- PV ----
        bf16x8 ap[2];
        #pragma unroll
        for (int ks = 0; ks < 2; ++ks)
            ap[ks] = *(const bf16x8*)
                &Pt[(w * 16 + lx) * 72 + ks * 32 + ly * 8];
        #pragma unroll
        for (int n = 0; n < 5; ++n) {
            f32x4 c = acc_o[n];
            #pragma unroll
            for (int ks = 0; ks < 2; ++ks) {
                const bf16x8 bv = *(const bf16x8*)
                    &Vt[(n * 16 + lx) * 64 + ((ks * 4 + ly) ^ (lx & 7)) * 8];
                c = __builtin_amdgcn_mfma_f32_16x16x32_bf16(ap[ks], bv, c, 0, 0, 0);
            }
            acc_o[n] = c;
        }
    }

    // ---- epilogue: normalize and store (out dims d = 0..64 per head) ----
    const int b = bh >> 4, h = bh & 15;
    #pragma unroll
    for (int r = 0; r < 4; ++r) {
        const int qrow = q0r + w * 16 + ly * 4 + r;
        const float inv = 1.0f / l_r[r];
        const size_t rowb = (size_t)b * T_ * DIM_ + (size_t)qrow * DIM_ + h * HD1_;
        #pragma unroll
        for (int n = 0; n < 4; ++n)
            Y[rowb + n * 16 + lx] = acc_o[n][r] * inv;
        if (lx == 0) Y[rowb + 64] = acc_o[4][r] * inv;
    }
}

// ---------------------------------------------------------------------------
// Workspace (68.12 MB, < round-1-proven 68.16 MB):
//  q/y [NELEM] f32 | k [NELEM] f32 | Wc [NP_*KPP_] bf16 |
//  QB,KB [32*2048*64] bf16 | VT [32*72*2048] bf16 | q0f,k0f [32*2048] f32
// ---------------------------------------------------------------------------
extern "C" void kernel_launch(void* const* d_in, const int* in_sizes, int n_in,
                              void* d_out, int out_size, void* d_ws, size_t ws_size,
                              hipStream_t stream)
{
    const float* x  = (const float*)d_in[0];
    const float* Wq = (const float*)d_in[1];
    const float* Wk = (const float*)d_in[2];
    const float* Wv = (const float*)d_in[3];
    const float* Wp = (const float*)d_in[4];

    float*  q   = (float*)d_ws;                 // also y (q dead after rotary)
    float*  k   = q + NELEM;
    __bf16* Wc  = (__bf16*)(k + NELEM);
    __bf16* QB  = Wc + (size_t)NP_ * KPP_;
    __bf16* KB  = QB + (size_t)NBH_ * T_ * 64;
    __bf16* VT  = KB + (size_t)NBH_ * T_ * 64;
    float*  q0f = (float*)(VT + (size_t)NBH_ * VTR_ * T_);
    float*  k0f = q0f + NBH_ * T_;
    float*  y   = q;
    float*  out = (float*)d_out;

    const int M = B_ * T_;
    dim3 blk(256);
    dim3 gcw((NP_ * SEGS_ + 255) / 256);
    dim3 gg(NP_ / 128, M / 128);
    dim3 grot((B_ * T_ * H_) / 4);

    convert_w<<<gcw, blk, 0, stream>>>(Wq, Wc);
    gemm_fused<0><<<gg, blk, 0, stream>>>(x, Wc, q, nullptr);
    convert_w<<<gcw, blk, 0, stream>>>(Wk, Wc);
    gemm_fused<0><<<gg, blk, 0, stream>>>(x, Wc, k, nullptr);
    convert_w<<<gcw, blk, 0, stream>>>(Wv, Wc);
    hipMemsetAsync(VT, 0, (size_t)NBH_ * VTR_ * T_ * 2, stream);
    gemm_fused<1><<<gg, blk, 0, stream>>>(x, Wc, nullptr, VT);

    rotary_conv<<<grot, blk, 0, stream>>>(q, QB, q0f);
    rotary_conv<<<grot, blk, 0, stream>>>(k, KB, k0f);

    attn_mfma2<<<dim3(T_ / 64, NBH_), blk, 0, stream>>>(QB, KB, VT, q0f, k0f, y);

    convert_w<<<gcw, blk, 0, stream>>>(Wp, Wc);
    gemm_fused<0><<<gg, blk, 0, stream>>>(y, Wc, out, nullptr);
}

// Round 8
// 401.886 us; speedup vs baseline: 3.9421x; 1.1816x over previous
//
#include <hip/hip_runtime.h>
#include <math.h>

#define B_   2
#define T_   2048
#define DIM_ 1040
#define H_   16
#define HD_  64
#define HD1_ 65
#define NELEM (B_*T_*DIM_)   // 4,259,840 floats per (b,t,dim) tensor

#define KP_   1056           // K padded to mult of 32 (1040 -> 1056)
#define KPP_  3168           // 3*KP_ : split-triplet K
#define NP_   1152           // weight rows padded to mult of 128
#define NP3_  3456           // 3*NP_ : fused QKV weight rows
#define SEGS_ 132            // KP_/8

#define NBH_  (B_*H_)        // 32
#define VTR_  72             // VT rows per bh (65 real + 7 zero)

typedef __attribute__((ext_vector_type(8))) __bf16 bf16x8;
typedef __attribute__((ext_vector_type(4))) float f32x4;
typedef __attribute__((ext_vector_type(8))) unsigned short ushort8;

static __device__ __forceinline__ unsigned pack_bf16(float lo, float hi) {
    __bf16 a = (__bf16)lo, c = (__bf16)hi;
    unsigned short ua, uc;
    __builtin_memcpy(&ua, &a, 2);
    __builtin_memcpy(&uc, &c, 2);
    return ((unsigned)uc << 16) | ua;
}

// ---------------------------------------------------------------------------
// Weight fp32 -> split-bf16 triplet (hi, lo, hi) conversion helpers.
// Paired with activation triplets (hi, hi, lo): bf16 dot over K''=3K
// computes hi*hi + hi*lo + lo*hi (drops only the ~2^-18 lo*lo term).
// ---------------------------------------------------------------------------
static __device__ __forceinline__ void conv_row_seg(
    const float* __restrict__ in, __bf16* __restrict__ out, int r, int s)
{
    float v[8];
    if (r < DIM_ && s < 130) {              // 130*8 = 1040 exactly
        const float4 f0 = *(const float4*)(in + (size_t)r * DIM_ + s * 8);
        const float4 f1 = *(const float4*)(in + (size_t)r * DIM_ + s * 8 + 4);
        v[0]=f0.x; v[1]=f0.y; v[2]=f0.z; v[3]=f0.w;
        v[4]=f1.x; v[5]=f1.y; v[6]=f1.z; v[7]=f1.w;
    } else {
        #pragma unroll
        for (int i = 0; i < 8; ++i) v[i] = 0.0f;
    }

    __bf16 t[24] __attribute__((aligned(16)));
    #pragma unroll
    for (int i = 0; i < 8; ++i) {
        const __bf16 hi = (__bf16)v[i];
        const __bf16 lo = (__bf16)(v[i] - (float)hi);
        t[3*i] = hi; t[3*i+1] = lo; t[3*i+2] = hi;
    }

    *(ushort8*)(out)      = *(const ushort8*)(t);
    *(ushort8*)(out + 8)  = *(const ushort8*)(t + 8);
    *(ushort8*)(out + 16) = *(const ushort8*)(t + 16);
}

// single weight (Wp)
__global__ __launch_bounds__(256)
void convert_w(const float* __restrict__ in, __bf16* __restrict__ out)
{
    const int gid = blockIdx.x * 256 + threadIdx.x;
    if (gid >= NP_ * SEGS_) return;
    const int r = gid / SEGS_, s = gid - r * SEGS_;
    conv_row_seg(in, out + (size_t)r * KPP_ + s * 24, r, s);
}

// fused Wq|Wk|Wv -> WcQKV[NP3_][KPP_]
__global__ __launch_bounds__(256)
void convert_w3(const float* __restrict__ Wq, const float* __restrict__ Wk,
                const float* __restrict__ Wv, __bf16* __restrict__ out)
{
    const int gid = blockIdx.x * 256 + threadIdx.x;
    if (gid >= NP3_ * SEGS_) return;
    const int r = gid / SEGS_, s = gid - r * SEGS_;
    const int seg = r / NP_, rr = r - seg * NP_;
    const float* in = (seg == 0) ? Wq : (seg == 1) ? Wk : Wv;
    conv_row_seg(in, out + (size_t)r * KPP_ + s * 24, rr, s);
}

// ---------------------------------------------------------------------------
// global->LDS async 16B
// ---------------------------------------------------------------------------
__device__ __forceinline__ void gload_lds16(const void* g, void* l) {
    __builtin_amdgcn_global_load_lds(
        (const __attribute__((address_space(1))) void*)g,
        (__attribute__((address_space(3))) void*)l, 16, 0, 0);
}

// ---------------------------------------------------------------------------
// Shared GEMM core: 128x128 tile over K''=KPP_; A fp32 converted to
// (hi,hi,lo) triplets on the fly; B pre-converted triplets.
// acc[4][4] f32x4 per lane, 4 waves in 2x2.
// ---------------------------------------------------------------------------
#define GEMM_CORE(A_, Bw_, N0_, M0_)                                          \
    __shared__ __bf16 As[128 * 96];                                           \
    __shared__ __bf16 Bs[128 * 96];                                           \
    const int tid  = threadIdx.x;                                             \
    const int lane = tid & 63;                                                \
    const int w    = tid >> 6;                                                \
    const int wr   = (w >> 1) * 64, wc = (w & 1) * 64;                        \
    const int ar  = tid >> 1, acg = (tid & 1) * 16;                           \
    const float* ga = A_ + (size_t)(M0_ + ar) * DIM_ + acg;                   \
    __bf16* la = As + ar * 96 + acg * 3;                                      \
    const __bf16* gb[6];                                                      \
    _Pragma("unroll")                                                         \
    for (int bb = 0; bb < 6; ++bb) {                                          \
        const int cid = bb * 256 + tid;                                       \
        const int br  = cid / 12, bc = cid - br * 12;                         \
        gb[bb] = Bw_ + (size_t)(N0_ + br) * KPP_ + bc * 8;                    \
    }                                                                         \
    __bf16* lb = Bs + tid * 8;                                                \
    f32x4 acc[4][4];                                                          \
    _Pragma("unroll")                                                         \
    for (int i = 0; i < 4; ++i)                                               \
        _Pragma("unroll")                                                     \
        for (int j = 0; j < 4; ++j) acc[i][j] = (f32x4){0.f, 0.f, 0.f, 0.f};  \
    const __bf16* pa = As + (wr + (lane & 15)) * 96 + (lane >> 4) * 8;        \
    const __bf16* pb = Bs + (wc + (lane & 15)) * 96 + (lane >> 4) * 8;        \
    for (int k0 = 0; k0 < DIM_; k0 += 32) {                                   \
        float vv[16];                                                         \
        if (k0 + acg < DIM_) {                                                \
            const float4 f0 = *(const float4*)(ga + k0);                      \
            const float4 f1 = *(const float4*)(ga + k0 + 4);                  \
            const float4 f2 = *(const float4*)(ga + k0 + 8);                  \
            const float4 f3 = *(const float4*)(ga + k0 + 12);                 \
            vv[0]=f0.x;  vv[1]=f0.y;  vv[2]=f0.z;  vv[3]=f0.w;                \
            vv[4]=f1.x;  vv[5]=f1.y;  vv[6]=f1.z;  vv[7]=f1.w;                \
            vv[8]=f2.x;  vv[9]=f2.y;  vv[10]=f2.z; vv[11]=f2.w;               \
            vv[12]=f3.x; vv[13]=f3.y; vv[14]=f3.z; vv[15]=f3.w;               \
        } else {                                                              \
            _Pragma("unroll")                                                 \
            for (int i = 0; i < 16; ++i) vv[i] = 0.0f;                        \
        }                                                                     \
        __syncthreads();                                                      \
        __bf16 tr[48] __attribute__((aligned(16)));                           \
        _Pragma("unroll")                                                     \
        for (int i = 0; i < 16; ++i) {                                        \
            const __bf16 hi = (__bf16)vv[i];                                  \
            const __bf16 lo = (__bf16)(vv[i] - (float)hi);                    \
            tr[3*i] = hi; tr[3*i+1] = hi; tr[3*i+2] = lo;                     \
        }                                                                     \
        _Pragma("unroll")                                                     \
        for (int s = 0; s < 6; ++s)                                           \
            *(ushort8*)(la + s * 8) = *(const ushort8*)(tr + s * 8);          \
        _Pragma("unroll")                                                     \
        for (int bb = 0; bb < 6; ++bb)                                        \
            gload_lds16(gb[bb] + k0 * 3, lb + bb * 2048);                     \
        __syncthreads();                                                      \
        _Pragma("unroll")                                                     \
        for (int ks = 0; ks < 3; ++ks) {                                      \
            bf16x8 a[4], b[4];                                                \
            _Pragma("unroll")                                                 \
            for (int i = 0; i < 4; ++i)                                       \
                a[i] = *(const bf16x8*)(pa + i * 16 * 96 + ks * 32);          \
            _Pragma("unroll")                                                 \
            for (int j = 0; j < 4; ++j)                                       \
                b[j] = *(const bf16x8*)(pb + j * 16 * 96 + ks * 32);          \
            _Pragma("unroll")                                                 \
            for (int i = 0; i < 4; ++i)                                       \
                _Pragma("unroll")                                             \
                for (int j = 0; j < 4; ++j)                                   \
                    acc[i][j] = __builtin_amdgcn_mfma_f32_16x16x32_bf16(      \
                        a[i], b[j], acc[i][j], 0, 0, 0);                      \
        }                                                                     \
    }

// ---------------------------------------------------------------------------
// Fused QKV GEMM: N=3456 (Q|K|V segments of 1152). Q,K -> fp32 row-major;
// V -> VT bf16 [bh][d][t] directly.
// ---------------------------------------------------------------------------
__global__ __launch_bounds__(256)
void gemm_qkv(const float* __restrict__ A, const __bf16* __restrict__ Bw,
              float* __restrict__ Cq, float* __restrict__ Ck,
              __bf16* __restrict__ VTout)
{
    const int m0 = blockIdx.y * 128, n0 = blockIdx.x * 128;
    GEMM_CORE(A, Bw, n0, m0)

    const int seg = n0 / NP_;                 // block fully inside one segment
    const int rbase = m0 + wr + (lane >> 4) * 4;
    const int cbase = n0 - seg * NP_ + wc + (lane & 15);

    if (seg < 2) {
        float* C = seg ? Ck : Cq;
        #pragma unroll
        for (int i = 0; i < 4; ++i)
            #pragma unroll
            for (int j = 0; j < 4; ++j) {
                const int n = cbase + j * 16;
                if (n < DIM_) {
                    #pragma unroll
                    for (int r = 0; r < 4; ++r)
                        C[(size_t)(rbase + i * 16 + r) * DIM_ + n] = acc[i][j][r];
                }
            }
    } else {
        #pragma unroll
        for (int i = 0; i < 4; ++i) {
            const int tg = rbase + i * 16;            // mult of 4
            const int bb = tg >> 11, tt = tg & (T_ - 1);
            #pragma unroll
            for (int j = 0; j < 4; ++j) {
                const int n = cbase + j * 16;
                if (n < DIM_) {
                    const int h = n / 65, d = n - h * 65;
                    const size_t off =
                        ((size_t)(bb * H_ + h) * VTR_ + d) * T_ + tt;
                    uint2 pk;
                    pk.x = pack_bf16(acc[i][j][0], acc[i][j][1]);
                    pk.y = pack_bf16(acc[i][j][2], acc[i][j][3]);
                    *(uint2*)(VTout + off) = pk;
                }
            }
        }
    }
}

// ---------------------------------------------------------------------------
// Output GEMM: C fp32 [M][1040] = y . Wp''^T
// ---------------------------------------------------------------------------
__global__ __launch_bounds__(256)
void gemm_out(const float* __restrict__ A, const __bf16* __restrict__ Bw,
              float* __restrict__ C)
{
    const int m0 = blockIdx.y * 128, n0 = blockIdx.x * 128;
    GEMM_CORE(A, Bw, n0, m0)

    const int rbase = m0 + wr + (lane >> 4) * 4;
    const int cbase = n0 + wc + (lane & 15);
    #pragma unroll
    for (int i = 0; i < 4; ++i)
        #pragma unroll
        for (int j = 0; j < 4; ++j) {
            const int n = cbase + j * 16;
            if (n < DIM_) {
                #pragma unroll
                for (int r = 0; r < 4; ++r)
                    C[(size_t)(rbase + i * 16 + r) * DIM_ + n] = acc[i][j][r];
            }
        }
}

// ---------------------------------------------------------------------------
// Fused rotary+convert for q AND k in one launch: reads fp32 GEMM output,
// writes XB bf16 [bh][t][64] (rotated spatial) + X0 fp32 [bh][t].
// One wave per (which, b, t, h).
// ---------------------------------------------------------------------------
__global__ __launch_bounds__(256)
void rotary2(const float* __restrict__ Xq, const float* __restrict__ Xk,
             __bf16* __restrict__ QB, __bf16* __restrict__ KB,
             float* __restrict__ Q0, float* __restrict__ K0)
{
    const int gwid = (blockIdx.x * 256 + threadIdx.x) >> 6;  // 0..131071
    const int lane = threadIdx.x & 63;
    const int which = gwid >> 16;          // 0 = q, 1 = k
    const int wid   = gwid & 65535;

    const int h  = wid & (H_ - 1);
    const int bt = wid >> 4;               // b*T + t
    const int t  = bt & (T_ - 1);
    const int b  = bt >> 11;
    const float* base = (which ? Xk : Xq) + (size_t)bt * DIM_ + h * HD1_;

    const int j = lane & 31;
    // ref: inv_freq = 1/10000^(2j/(HD-2eps)); (HD-2eps) rounds to 64.0 in fp32
    const float pw = powf(10000.0f, (float)j * (1.0f / 32.0f));
    const float fr = (float)t * (1.0f / pw);
    const float cs = cosf(fr);
    const float sn = sinf(fr);

    const float x1 = base[1 + j];
    const float x2 = base[33 + j];

    float rot = (lane < 32) ? (x1 * cs + x2 * sn)
                            : (x2 * cs - x1 * sn);
    rot = fminf(fmaxf(rot, -1000.0f), 1000.0f);

    float sq = rot * rot;
    #pragma unroll
    for (int off = 32; off >= 1; off >>= 1)
        sq += __shfl_xor(sq, off, 64);
    sq = fminf(fmaxf(sq, 0.0f), 1.0e6f);

    const float x0 = sqrtf((1.0f + sq) + 1.0e-6f);

    const size_t bht = (size_t)(b * H_ + h) * T_ + t;
    (which ? KB : QB)[bht * 64 + lane] = (__bf16)rot;
    if (lane == 0) (which ? K0 : Q0)[bht] = x0;
}

// ---------------------------------------------------------------------------
// MFMA attention v2 (XCD-local grid: blockIdx.x = bh so bid%8 = bh%8 —
// all q-blocks of a head share one XCD's L2 for K/V).
// ---------------------------------------------------------------------------
__global__ __launch_bounds__(256)
void attn_mfma2(const __bf16* __restrict__ QB, const __bf16* __restrict__ KB,
                const __bf16* __restrict__ VT, const float* __restrict__ Q0,
                const float* __restrict__ K0, float* __restrict__ Y)
{
    __shared__ __bf16 Qt[64 * 64] __attribute__((aligned(16)));
    __shared__ __bf16 Kt[64 * 64] __attribute__((aligned(16)));
    __shared__ __bf16 Vt[80 * 64] __attribute__((aligned(16)));
    __shared__ __bf16 Pt[64 * 72] __attribute__((aligned(16)));
    __shared__ float q0s[64], k0s[64];

    const int tid  = threadIdx.x;
    const int lane = tid & 63;
    const int w    = tid >> 6;
    const int lx   = lane & 15;
    const int ly   = lane >> 4;
    const int bh   = blockIdx.x;           // XCD-local: bid%8 == bh%8
    const int q0r  = blockIdx.y * 64;

    const __bf16* QBb = QB + (size_t)bh * T_ * 64;
    const __bf16* KBb = KB + (size_t)bh * T_ * 64;
    const __bf16* VTb = VT + (size_t)bh * VTR_ * T_;

    #pragma unroll
    for (int qi = 0; qi < 2; ++qi) {
        const int cid = qi * 256 + tid;
        const int r = cid >> 3, j = cid & 7;
        gload_lds16(QBb + (size_t)(q0r + r) * 64 + (j ^ (r & 7)) * 8,
                    Qt + cid * 8);
    }
    ((unsigned*)Vt)[2304 + tid] = 0u;      // rows 72..79
    if (tid < 64) q0s[tid] = Q0[(size_t)bh * T_ + q0r + tid];

    const __bf16* gk[2]; __bf16* lk[2];
    #pragma unroll
    for (int qi = 0; qi < 2; ++qi) {
        const int cid = qi * 256 + tid;
        const int r = cid >> 3, j = cid & 7;
        gk[qi] = KBb + r * 64 + (j ^ (r & 7)) * 8;
        lk[qi] = Kt + cid * 8;
    }
    const __bf16* gv[3]; __bf16* lv[3];
    #pragma unroll
    for (int qi = 0; qi < 3; ++qi) {
        const int cid = qi * 256 + tid;
        const int d = cid >> 3, j = cid & 7;
        gv[qi] = VTb + (size_t)(d < VTR_ ? d : 0) * T_ + (j ^ (d & 7)) * 8;
        lv[qi] = Vt + cid * 8;
    }

    f32x4 acc_o[5];
    #pragma unroll
    for (int n = 0; n < 5; ++n) acc_o[n] = (f32x4){0.f, 0.f, 0.f, 0.f};
    float m_r[4] = {-1.0e30f, -1.0e30f, -1.0e30f, -1.0e30f};
    float l_r[4] = {0.f, 0.f, 0.f, 0.f};

    for (int s0 = 0; s0 < T_; s0 += 64) {
        __syncthreads();

        gload_lds16(gk[0] + (size_t)s0 * 64, lk[0]);
        gload_lds16(gk[1] + (size_t)s0 * 64, lk[1]);
        gload_lds16(gv[0] + s0, lv[0]);
        gload_lds16(gv[1] + s0, lv[1]);
        if (tid < 64) {
            gload_lds16(gv[2] + s0, lv[2]);
            k0s[tid] = K0[(size_t)bh * T_ + s0 + tid];
        }
        __syncthreads();

        // ---- QK^T (spatial, 64 dims = 2 k-steps) ----
        bf16x8 aq[2];
        #pragma unroll
        for (int ks = 0; ks < 2; ++ks)
            aq[ks] = *(const bf16x8*)
                &Qt[(w * 16 + lx) * 64 + ((ks * 4 + ly) ^ (lx & 7)) * 8];

        f32x4 sc[4];
        #pragma unroll
        for (int n = 0; n < 4; ++n) {
            f32x4 c = (f32x4){0.f, 0.f, 0.f, 0.f};
            #pragma unroll
            for (int ks = 0; ks < 2; ++ks) {
                const bf16x8 bk = *(const bf16x8*)
                    &Kt[(n * 16 + lx) * 64 + ((ks * 4 + ly) ^ (lx & 7)) * 8];
                c = __builtin_amdgcn_mfma_f32_16x16x32_bf16(aq[ks], bk, c, 0, 0, 0);
            }
            sc[n] = c;
        }

        // ---- scores: fp32 Lorentz fix, scale, clip ----
        float q0v[4], k0v[4];
        #pragma unroll
        for (int r = 0; r < 4; ++r) q0v[r] = q0s[w * 16 + ly * 4 + r];
        #pragma unroll
        for (int n = 0; n < 4; ++n) k0v[n] = k0s[n * 16 + lx];

        float p[4][4];
        float rmax[4] = {-1.0e30f, -1.0e30f, -1.0e30f, -1.0e30f};
        #pragma unroll
        for (int n = 0; n < 4; ++n)
            #pragma unroll
            for (int r = 0; r < 4; ++r) {
                float s = (sc[n][r] - q0v[r] * k0v[n]) * 0.125f;
                s = fminf(fmaxf(s, -100.0f), 100.0f);
                p[n][r] = s;
                rmax[r] = fmaxf(rmax[r], s);
            }
        #pragma unroll
        for (int r = 0; r < 4; ++r) {
            rmax[r] = fmaxf(rmax[r], __shfl_xor(rmax[r], 1, 64));
            rmax[r] = fmaxf(rmax[r], __shfl_xor(rmax[r], 2, 64));
            rmax[r] = fmaxf(rmax[r], __shfl_xor(rmax[r], 4, 64));
            rmax[r] = fmaxf(rmax[r], __shfl_xor(rmax[r], 8, 64));
        }
        float alpha[4], rsum[4];
        #pragma unroll
        for (int r = 0; r < 4; ++r) {
            const float mn = fmaxf(m_r[r], rmax[r]);
            alpha[r] = __expf(m_r[r] - mn);
            m_r[r] = mn;
            rsum[r] = 0.0f;
        }
        #pragma unroll
        for (int n = 0; n < 4; ++n)
            #pragma unroll
            for (int r = 0; r < 4; ++r) {
                p[n][r] = __expf(p[n][r] - m_r[r]);
                rsum[r] += p[n][r];
            }
        #pragma unroll
        for (int r = 0; r < 4; ++r) {
            rsum[r] += __shfl_xor(rsum[r], 1, 64);
            rsum[r] += __shfl_xor(rsum[r], 2, 64);
            rsum[r] += __shfl_xor(rsum[r], 4, 64);
            rsum[r] += __shfl_xor(rsum[r], 8, 64);
            l_r[r] = l_r[r] * alpha[r] + rsum[r];
        }

        // ---- P bf16 -> LDS (C-layout); same wave re-reads as A-operand ----
        #pragma unroll
        for (int n = 0; n < 4; ++n)
            #pragma unroll
            for (int r = 0; r < 4; ++r)
                Pt[(w * 16 + ly * 4 + r) * 72 + n * 16 + lx] = (__bf16)p[n][r];

        #pragma unroll
        for (int n = 0; n < 5; ++n)
            #pragma unroll
            for (int r = 0; r < 4; ++r) acc_o[n][r] *= alpha[r];

        // ---- PV ----
        bf16x8 ap[2];
        #pragma unroll
        for (int ks = 0; ks < 2; ++ks)
            ap[ks] = *(const bf16x8*)
                &Pt[(w * 16 + lx) * 72 + ks * 32 + ly * 8];
        #pragma unroll
        for (int n = 0; n < 5; ++n) {
            f32x4 c = acc_o[n];
            #pragma unroll
            for (int ks = 0; ks < 2; ++ks) {
                const bf16x8 bv = *(const bf16x8*)
                    &Vt[(n * 16 + lx) * 64 + ((ks * 4 + ly) ^ (lx & 7)) * 8];
                c = __builtin_amdgcn_mfma_f32_16x16x32_bf16(ap[ks], bv, c, 0, 0, 0);
            }
            acc_o[n] = c;
        }
    }

    // ---- epilogue ----
    const int b = bh >> 4, h = bh & 15;
    #pragma unroll
    for (int r = 0; r < 4; ++r) {
        const int qrow = q0r + w * 16 + ly * 4 + r;
        const float inv = 1.0f / l_r[r];
        const size_t rowb = (size_t)b * T_ * DIM_ + (size_t)qrow * DIM_ + h * HD1_;
        #pragma unroll
        for (int n = 0; n < 4; ++n)
            Y[rowb + n * 16 + lx] = acc_o[n][r] * inv;
        if (lx == 0) Y[rowb + 64] = acc_o[4][r] * inv;
    }
}

// ---------------------------------------------------------------------------
// Workspace (65.4 MB, < proven 68.1 MB):
//  q/y [NELEM] f32 | k [NELEM] f32 (-> WcP after rotary) |
//  WcQKV [NP3_*KPP_] bf16 (-> QB|KB|q0f|k0f after QKV GEMM) | VT bf16
// ---------------------------------------------------------------------------
extern "C" void kernel_launch(void* const* d_in, const int* in_sizes, int n_in,
                              void* d_out, int out_size, void* d_ws, size_t ws_size,
                              hipStream_t stream)
{
    const float* x  = (const float*)d_in[0];
    const float* Wq = (const float*)d_in[1];
    const float* Wk = (const float*)d_in[2];
    const float* Wv = (const float*)d_in[3];
    const float* Wp = (const float*)d_in[4];

    float*  q     = (float*)d_ws;                       // also y
    float*  k     = q + NELEM;                          // also WcP space
    __bf16* WcQKV = (__bf16*)(k + NELEM);               // 21.9 MB
    __bf16* VT    = WcQKV + (size_t)NP3_ * KPP_;        // 9.44 MB

    // aliases into WcQKV (dead after QKV GEMM):
    __bf16* QB  = WcQKV;
    __bf16* KB  = QB + (size_t)NBH_ * T_ * 64;
    float*  q0f = (float*)(KB + (size_t)NBH_ * T_ * 64);
    float*  k0f = q0f + NBH_ * T_;
    // alias into k (dead after rotary):
    __bf16* WcP = (__bf16*)k;

    float* y   = q;
    float* out = (float*)d_out;

    const int M = B_ * T_;
    dim3 blk(256);

    convert_w3<<<dim3(NP3_ * SEGS_ / 256), blk, 0, stream>>>(Wq, Wk, Wv, WcQKV);
    hipMemsetAsync(VT, 0, (size_t)NBH_ * VTR_ * T_ * 2, stream);
    gemm_qkv<<<dim3(NP3_ / 128, M / 128), blk, 0, stream>>>(x, WcQKV, q, k, VT);

    rotary2<<<dim3(2 * (B_ * T_ * H_) / 4), blk, 0, stream>>>(
        q, k, QB, KB, q0f, k0f);

    attn_mfma2<<<dim3(NBH_, T_ / 64), blk, 0, stream>>>(QB, KB, VT, q0f, k0f, y);

    convert_w<<<dim3((NP_ * SEGS_ + 255) / 256), blk, 0, stream>>>(Wp, WcP);
    gemm_out<<<dim3(NP_ / 128, M / 128), blk, 0, stream>>>(y, WcP, out);
}

// Round 9
// 399.518 us; speedup vs baseline: 3.9654x; 1.0059x over previous
//
#include <hip/hip_runtime.h>
#include <math.h>

#define B_   2
#define T_   2048
#define DIM_ 1040
#define H_   16
#define HD_  64
#define HD1_ 65
#define NELEM (B_*T_*DIM_)   // 4,259,840 floats per (b,t,dim) tensor

#define KP_   1056           // K padded to mult of 32 (1040 -> 1056)
#define KPP_  3168           // 3*KP_ : split-triplet K
#define NP_   1152           // weight rows padded to mult of 128
#define NP3_  3456           // 3*NP_ : fused QKV weight rows
#define SEGS_ 132            // KP_/8

#define NBH_  (B_*H_)        // 32
#define VTR_  72             // VT rows per bh (65 real + 7 zero)

typedef __attribute__((ext_vector_type(8))) __bf16 bf16x8;
typedef __attribute__((ext_vector_type(4))) float f32x4;
typedef __attribute__((ext_vector_type(8))) unsigned short ushort8;

static __device__ __forceinline__ unsigned pack_bf16(float lo, float hi) {
    __bf16 a = (__bf16)lo, c = (__bf16)hi;
    unsigned short ua, uc;
    __builtin_memcpy(&ua, &a, 2);
    __builtin_memcpy(&uc, &c, 2);
    return ((unsigned)uc << 16) | ua;
}

// ---------------------------------------------------------------------------
// Weight fp32 -> split-bf16 triplet (hi, lo, hi) conversion helpers.
// Paired with activation triplets (hi, hi, lo): bf16 dot over K''=3K
// computes hi*hi + hi*lo + lo*hi (drops only the ~2^-18 lo*lo term).
// ---------------------------------------------------------------------------
static __device__ __forceinline__ void conv_row_seg(
    const float* __restrict__ in, __bf16* __restrict__ out, int r, int s)
{
    float v[8];
    if (r < DIM_ && s < 130) {              // 130*8 = 1040 exactly
        const float4 f0 = *(const float4*)(in + (size_t)r * DIM_ + s * 8);
        const float4 f1 = *(const float4*)(in + (size_t)r * DIM_ + s * 8 + 4);
        v[0]=f0.x; v[1]=f0.y; v[2]=f0.z; v[3]=f0.w;
        v[4]=f1.x; v[5]=f1.y; v[6]=f1.z; v[7]=f1.w;
    } else {
        #pragma unroll
        for (int i = 0; i < 8; ++i) v[i] = 0.0f;
    }

    __bf16 t[24] __attribute__((aligned(16)));
    #pragma unroll
    for (int i = 0; i < 8; ++i) {
        const __bf16 hi = (__bf16)v[i];
        const __bf16 lo = (__bf16)(v[i] - (float)hi);
        t[3*i] = hi; t[3*i+1] = lo; t[3*i+2] = hi;
    }

    *(ushort8*)(out)      = *(const ushort8*)(t);
    *(ushort8*)(out + 8)  = *(const ushort8*)(t + 8);
    *(ushort8*)(out + 16) = *(const ushort8*)(t + 16);
}

// single weight (Wp)
__global__ __launch_bounds__(256)
void convert_w(const float* __restrict__ in, __bf16* __restrict__ out)
{
    const int gid = blockIdx.x * 256 + threadIdx.x;
    if (gid >= NP_ * SEGS_) return;
    const int r = gid / SEGS_, s = gid - r * SEGS_;
    conv_row_seg(in, out + (size_t)r * KPP_ + s * 24, r, s);
}

// fused Wq|Wk|Wv -> WcQKV[NP3_][KPP_]
__global__ __launch_bounds__(256)
void convert_w3(const float* __restrict__ Wq, const float* __restrict__ Wk,
                const float* __restrict__ Wv, __bf16* __restrict__ out)
{
    const int gid = blockIdx.x * 256 + threadIdx.x;
    if (gid >= NP3_ * SEGS_) return;
    const int r = gid / SEGS_, s = gid - r * SEGS_;
    const int seg = r / NP_, rr = r - seg * NP_;
    const float* in = (seg == 0) ? Wq : (seg == 1) ? Wk : Wv;
    conv_row_seg(in, out + (size_t)r * KPP_ + s * 24, rr, s);
}

// ---------------------------------------------------------------------------
// global->LDS async 16B
// ---------------------------------------------------------------------------
__device__ __forceinline__ void gload_lds16(const void* g, void* l) {
    __builtin_amdgcn_global_load_lds(
        (const __attribute__((address_space(1))) void*)g,
        (__attribute__((address_space(3))) void*)l, 16, 0, 0);
}

// ---------------------------------------------------------------------------
// Shared GEMM core: 128x128 tile over K''=KPP_; A fp32 converted to
// (hi,hi,lo) triplets on the fly; B pre-converted triplets.
// ---------------------------------------------------------------------------
#define GEMM_CORE(A_, Bw_, N0_, M0_)                                          \
    __shared__ __bf16 As[128 * 96];                                           \
    __shared__ __bf16 Bs[128 * 96];                                           \
    const int tid  = threadIdx.x;                                             \
    const int lane = tid & 63;                                                \
    const int w    = tid >> 6;                                                \
    const int wr   = (w >> 1) * 64, wc = (w & 1) * 64;                        \
    const int ar  = tid >> 1, acg = (tid & 1) * 16;                           \
    const float* ga = A_ + (size_t)(M0_ + ar) * DIM_ + acg;                   \
    __bf16* la = As + ar * 96 + acg * 3;                                      \
    const __bf16* gb[6];                                                      \
    _Pragma("unroll")                                                         \
    for (int bb = 0; bb < 6; ++bb) {                                          \
        const int cid = bb * 256 + tid;                                       \
        const int br  = cid / 12, bc = cid - br * 12;                         \
        gb[bb] = Bw_ + (size_t)(N0_ + br) * KPP_ + bc * 8;                    \
    }                                                                         \
    __bf16* lb = Bs + tid * 8;                                                \
    f32x4 acc[4][4];                                                          \
    _Pragma("unroll")                                                         \
    for (int i = 0; i < 4; ++i)                                               \
        _Pragma("unroll")                                                     \
        for (int j = 0; j < 4; ++j) acc[i][j] = (f32x4){0.f, 0.f, 0.f, 0.f};  \
    const __bf16* pa = As + (wr + (lane & 15)) * 96 + (lane >> 4) * 8;        \
    const __bf16* pb = Bs + (wc + (lane & 15)) * 96 + (lane >> 4) * 8;        \
    for (int k0 = 0; k0 < DIM_; k0 += 32) {                                   \
        float vv[16];                                                         \
        if (k0 + acg < DIM_) {                                                \
            const float4 f0 = *(const float4*)(ga + k0);                      \
            const float4 f1 = *(const float4*)(ga + k0 + 4);                  \
            const float4 f2 = *(const float4*)(ga + k0 + 8);                  \
            const float4 f3 = *(const float4*)(ga + k0 + 12);                 \
            vv[0]=f0.x;  vv[1]=f0.y;  vv[2]=f0.z;  vv[3]=f0.w;                \
            vv[4]=f1.x;  vv[5]=f1.y;  vv[6]=f1.z;  vv[7]=f1.w;                \
            vv[8]=f2.x;  vv[9]=f2.y;  vv[10]=f2.z; vv[11]=f2.w;               \
            vv[12]=f3.x; vv[13]=f3.y; vv[14]=f3.z; vv[15]=f3.w;               \
        } else {                                                              \
            _Pragma("unroll")                                                 \
            for (int i = 0; i < 16; ++i) vv[i] = 0.0f;                        \
        }                                                                     \
        __syncthreads();                                                      \
        __bf16 tr[48] __attribute__((aligned(16)));                           \
        _Pragma("unroll")                                                     \
        for (int i = 0; i < 16; ++i) {                                        \
            const __bf16 hi = (__bf16)vv[i];                                  \
            const __bf16 lo = (__bf16)(vv[i] - (float)hi);                    \
            tr[3*i] = hi; tr[3*i+1] = hi; tr[3*i+2] = lo;                     \
        }                                                                     \
        _Pragma("unroll")                                                     \
        for (int s = 0; s < 6; ++s)                                           \
            *(ushort8*)(la + s * 8) = *(const ushort8*)(tr + s * 8);          \
        _Pragma("unroll")                                                     \
        for (int bb = 0; bb < 6; ++bb)                                        \
            gload_lds16(gb[bb] + k0 * 3, lb + bb * 2048);                     \
        __syncthreads();                                                      \
        _Pragma("unroll")                                                     \
        for (int ks = 0; ks < 3; ++ks) {                                      \
            bf16x8 a[4], b[4];                                                \
            _Pragma("unroll")                                                 \
            for (int i = 0; i < 4; ++i)                                       \
                a[i] = *(const bf16x8*)(pa + i * 16 * 96 + ks * 32);          \
            _Pragma("unroll")                                                 \
            for (int j = 0; j < 4; ++j)                                       \
                b[j] = *(const bf16x8*)(pb + j * 16 * 96 + ks * 32);          \
            __builtin_amdgcn_s_setprio(1);                                    \
            _Pragma("unroll")                                                 \
            for (int i = 0; i < 4; ++i)                                       \
                _Pragma("unroll")                                             \
                for (int j = 0; j < 4; ++j)                                   \
                    acc[i][j] = __builtin_amdgcn_mfma_f32_16x16x32_bf16(      \
                        a[i], b[j], acc[i][j], 0, 0, 0);                      \
            __builtin_amdgcn_s_setprio(0);                                    \
        }                                                                     \
    }

// ---------------------------------------------------------------------------
// Fused QKV GEMM (1D grid 864 = 8*108, XCD-bijective n-major swizzle):
// each XCD covers a contiguous gid range -> ~4 B-strips (3.2 MB) L2-resident.
// Q,K -> fp32 row-major; V -> VT bf16 [bh][d][t] directly.
// ---------------------------------------------------------------------------
__global__ __launch_bounds__(256)
void gemm_qkv(const float* __restrict__ A, const __bf16* __restrict__ Bw,
              float* __restrict__ Cq, float* __restrict__ Ck,
              __bf16* __restrict__ VTout)
{
    const int bid = blockIdx.x;
    const int gid = (bid & 7) * 108 + (bid >> 3);   // 864 = 8 * 108
    const int n0  = (gid >> 5) * 128;               // n slowest within XCD
    const int m0  = (gid & 31) * 128;
    GEMM_CORE(A, Bw, n0, m0)

    const int seg = n0 / NP_;                 // block fully inside one segment
    const int rbase = m0 + wr + (lane >> 4) * 4;
    const int cbase = n0 - seg * NP_ + wc + (lane & 15);

    if (seg < 2) {
        float* C = seg ? Ck : Cq;
        #pragma unroll
        for (int i = 0; i < 4; ++i)
            #pragma unroll
            for (int j = 0; j < 4; ++j) {
                const int n = cbase + j * 16;
                if (n < DIM_) {
                    #pragma unroll
                    for (int r = 0; r < 4; ++r)
                        C[(size_t)(rbase + i * 16 + r) * DIM_ + n] = acc[i][j][r];
                }
            }
    } else {
        #pragma unroll
        for (int i = 0; i < 4; ++i) {
            const int tg = rbase + i * 16;            // mult of 4
            const int bb = tg >> 11, tt = tg & (T_ - 1);
            #pragma unroll
            for (int j = 0; j < 4; ++j) {
                const int n = cbase + j * 16;
                if (n < DIM_) {
                    const int h = n / 65, d = n - h * 65;
                    const size_t off =
                        ((size_t)(bb * H_ + h) * VTR_ + d) * T_ + tt;
                    uint2 pk;
                    pk.x = pack_bf16(acc[i][j][0], acc[i][j][1]);
                    pk.y = pack_bf16(acc[i][j][2], acc[i][j][3]);
                    *(uint2*)(VTout + off) = pk;
                }
            }
        }
    }
}

// ---------------------------------------------------------------------------
// Output GEMM (1D grid 288 = 8*36, same XCD swizzle): C fp32 = y . Wp''^T
// ---------------------------------------------------------------------------
__global__ __launch_bounds__(256)
void gemm_out(const float* __restrict__ A, const __bf16* __restrict__ Bw,
              float* __restrict__ C)
{
    const int bid = blockIdx.x;
    const int gid = (bid & 7) * 36 + (bid >> 3);    // 288 = 8 * 36
    const int n0  = (gid >> 5) * 128;
    const int m0  = (gid & 31) * 128;
    GEMM_CORE(A, Bw, n0, m0)

    const int rbase = m0 + wr + (lane >> 4) * 4;
    const int cbase = n0 + wc + (lane & 15);
    #pragma unroll
    for (int i = 0; i < 4; ++i)
        #pragma unroll
        for (int j = 0; j < 4; ++j) {
            const int n = cbase + j * 16;
            if (n < DIM_) {
                #pragma unroll
                for (int r = 0; r < 4; ++r)
                    C[(size_t)(rbase + i * 16 + r) * DIM_ + n] = acc[i][j][r];
            }
        }
}

// ---------------------------------------------------------------------------
// Fused rotary+convert for q AND k: writes XB bf16 [bh][t][64] + X0 fp32.
// ---------------------------------------------------------------------------
__global__ __launch_bounds__(256)
void rotary2(const float* __restrict__ Xq, const float* __restrict__ Xk,
             __bf16* __restrict__ QB, __bf16* __restrict__ KB,
             float* __restrict__ Q0, float* __restrict__ K0)
{
    const int gwid = (blockIdx.x * 256 + threadIdx.x) >> 6;  // 0..131071
    const int lane = threadIdx.x & 63;
    const int which = gwid >> 16;          // 0 = q, 1 = k
    const int wid   = gwid & 65535;

    const int h  = wid & (H_ - 1);
    const int bt = wid >> 4;               // b*T + t
    const int t  = bt & (T_ - 1);
    const int b  = bt >> 11;
    const float* base = (which ? Xk : Xq) + (size_t)bt * DIM_ + h * HD1_;

    const int j = lane & 31;
    // ref: inv_freq = 1/10000^(2j/(HD-2eps)); (HD-2eps) rounds to 64.0 in fp32
    const float pw = powf(10000.0f, (float)j * (1.0f / 32.0f));
    const float fr = (float)t * (1.0f / pw);
    const float cs = cosf(fr);
    const float sn = sinf(fr);

    const float x1 = base[1 + j];
    const float x2 = base[33 + j];

    float rot = (lane < 32) ? (x1 * cs + x2 * sn)
                            : (x2 * cs - x1 * sn);
    rot = fminf(fmaxf(rot, -1000.0f), 1000.0f);

    float sq = rot * rot;
    #pragma unroll
    for (int off = 32; off >= 1; off >>= 1)
        sq += __shfl_xor(sq, off, 64);
    sq = fminf(fmaxf(sq, 0.0f), 1.0e6f);

    const float x0 = sqrtf((1.0f + sq) + 1.0e-6f);

    const size_t bht = (size_t)(b * H_ + h) * T_ + t;
    (which ? KB : QB)[bht * 64 + lane] = (__bf16)rot;
    if (lane == 0) (which ? K0 : Q0)[bht] = x0;
}

// ---------------------------------------------------------------------------
// MFMA attention v3: QBLK=128 (2 row-tiles/wave), K/V double-buffered with
// one-barrier-per-tile prefetch (stage issued before compute, drained by the
// next __syncthreads), setprio around MFMA clusters. Grid (bh=32, qblk=16):
// bid%8 = bh%8 keeps each head's K/V on one XCD's L2.
// ---------------------------------------------------------------------------
__global__ __launch_bounds__(256)
void attn_mfma3(const __bf16* __restrict__ QB, const __bf16* __restrict__ KB,
                const __bf16* __restrict__ VT, const float* __restrict__ Q0,
                const float* __restrict__ K0, float* __restrict__ Y)
{
    __shared__ __bf16 Qt[128 * 64] __attribute__((aligned(16)));
    __shared__ __bf16 Kt[2][64 * 64] __attribute__((aligned(16)));
    __shared__ __bf16 Vt[2][80 * 64] __attribute__((aligned(16)));
    __shared__ __bf16 Pt[128 * 72] __attribute__((aligned(16)));

    const int tid  = threadIdx.x;
    const int lane = tid & 63;
    const int w    = tid >> 6;
    const int lx   = lane & 15;
    const int ly   = lane >> 4;
    const int bh   = blockIdx.x;           // XCD-local: bid%8 == bh%8
    const int q0r  = blockIdx.y * 128;

    const __bf16* QBb = QB + (size_t)bh * T_ * 64;
    const __bf16* KBb = KB + (size_t)bh * T_ * 64;
    const __bf16* VTb = VT + (size_t)bh * VTR_ * T_;
    const float*  Q0b = Q0 + (size_t)bh * T_;
    const float*  K0b = K0 + (size_t)bh * T_;

    // ---- one-time: Q tile (128 rows, swizzled source), Vt zero rows ----
    #pragma unroll
    for (int qi = 0; qi < 4; ++qi) {
        const int cid = qi * 256 + tid;
        const int r = cid >> 3, j = cid & 7;
        gload_lds16(QBb + (size_t)(q0r + r) * 64 + (j ^ (r & 7)) * 8,
                    Qt + cid * 8);
    }
    ((unsigned*)Vt[0])[2304 + tid] = 0u;   // rows 72..79
    ((unsigned*)Vt[1])[2304 + tid] = 0u;

    // per-lane q0 (register-resident, 2 row-tiles x 4 rows)
    float q0v[2][4];
    #pragma unroll
    for (int t = 0; t < 2; ++t)
        #pragma unroll
        for (int r = 0; r < 4; ++r)
            q0v[t][r] = Q0b[q0r + t * 64 + w * 16 + ly * 4 + r];

    // staging source offsets (element offsets into KBb / VTb, + s0-dependent)
    int offk[2], offv[3];
    #pragma unroll
    for (int qi = 0; qi < 2; ++qi) {
        const int cid = qi * 256 + tid;
        const int r = cid >> 3, j = cid & 7;
        offk[qi] = r * 64 + (j ^ (r & 7)) * 8;     // + s0*64
    }
    #pragma unroll
    for (int qi = 0; qi < 3; ++qi) {
        const int cid = qi * 256 + tid;
        const int d = cid >> 3, j = cid & 7;
        offv[qi] = d * T_ + (j ^ (d & 7)) * 8;     // + s0
    }

    // prologue: stage tile 0 into buffer 0; prefetch k0 for tile 0
    #pragma unroll
    for (int qi = 0; qi < 2; ++qi)
        gload_lds16(KBb + offk[qi], &Kt[0][(qi * 256 + tid) * 8]);
    gload_lds16(VTb + offv[0], &Vt[0][tid * 8]);
    gload_lds16(VTb + offv[1], &Vt[0][(256 + tid) * 8]);
    if (tid < 64) gload_lds16(VTb + offv[2], &Vt[0][(512 + tid) * 8]);

    float k0nxt[4];
    #pragma unroll
    for (int n = 0; n < 4; ++n) k0nxt[n] = K0b[n * 16 + lx];

    f32x4 acc_o[2][5];
    #pragma unroll
    for (int t = 0; t < 2; ++t)
        #pragma unroll
        for (int n = 0; n < 5; ++n) acc_o[t][n] = (f32x4){0.f, 0.f, 0.f, 0.f};
    float m_r[2][4], l_r[2][4];
    #pragma unroll
    for (int t = 0; t < 2; ++t)
        #pragma unroll
        for (int r = 0; r < 4; ++r) { m_r[t][r] = -1.0e30f; l_r[t][r] = 0.f; }

    int cur = 0;
    for (int it = 0; it < T_ / 64; ++it) {
        const int s0 = it * 64;
        __syncthreads();   // buf[cur] staged (prev iter's prefetch drained)

        float k0cur[4];
        #pragma unroll
        for (int n = 0; n < 4; ++n) k0cur[n] = k0nxt[n];

        if (it + 1 < T_ / 64) {            // prefetch next tile into buf^1
            const int s1 = s0 + 64;
            #pragma unroll
            for (int qi = 0; qi < 2; ++qi)
                gload_lds16(KBb + (size_t)s1 * 64 + offk[qi],
                            &Kt[cur ^ 1][(qi * 256 + tid) * 8]);
            gload_lds16(VTb + s1 + offv[0], &Vt[cur ^ 1][tid * 8]);
            gload_lds16(VTb + s1 + offv[1], &Vt[cur ^ 1][(256 + tid) * 8]);
            if (tid < 64)
                gload_lds16(VTb + s1 + offv[2], &Vt[cur ^ 1][(512 + tid) * 8]);
            #pragma unroll
            for (int n = 0; n < 4; ++n) k0nxt[n] = K0b[s1 + n * 16 + lx];
        }

        #pragma unroll
        for (int t = 0; t < 2; ++t) {
            const int rb = t * 64 + w * 16;

            // ---- QK^T ----
            bf16x8 aq[2];
            #pragma unroll
            for (int ks = 0; ks < 2; ++ks)
                aq[ks] = *(const bf16x8*)
                    &Qt[(rb + lx) * 64 + ((ks * 4 + ly) ^ (lx & 7)) * 8];

            f32x4 sc[4];
            __builtin_amdgcn_s_setprio(1);
            #pragma unroll
            for (int n = 0; n < 4; ++n) {
                f32x4 c = (f32x4){0.f, 0.f, 0.f, 0.f};
                #pragma unroll
                for (int ks = 0; ks < 2; ++ks) {
                    const bf16x8 bk = *(const bf16x8*)
                        &Kt[cur][(n * 16 + lx) * 64 +
                                 ((ks * 4 + ly) ^ (lx & 7)) * 8];
                    c = __builtin_amdgcn_mfma_f32_16x16x32_bf16(
                        aq[ks], bk, c, 0, 0, 0);
                }
                sc[n] = c;
            }
            __builtin_amdgcn_s_setprio(0);

            // ---- scores: fp32 Lorentz fix, scale, clip ----
            float p[4][4];
            float rmax[4] = {-1.0e30f, -1.0e30f, -1.0e30f, -1.0e30f};
            #pragma unroll
            for (int n = 0; n < 4; ++n)
                #pragma unroll
                for (int r = 0; r < 4; ++r) {
                    float s = (sc[n][r] - q0v[t][r] * k0cur[n]) * 0.125f;
                    s = fminf(fmaxf(s, -100.0f), 100.0f);
                    p[n][r] = s;
                    rmax[r] = fmaxf(rmax[r], s);
                }
            #pragma unroll
            for (int r = 0; r < 4; ++r) {
                rmax[r] = fmaxf(rmax[r], __shfl_xor(rmax[r], 1, 64));
                rmax[r] = fmaxf(rmax[r], __shfl_xor(rmax[r], 2, 64));
                rmax[r] = fmaxf(rmax[r], __shfl_xor(rmax[r], 4, 64));
                rmax[r] = fmaxf(rmax[r], __shfl_xor(rmax[r], 8, 64));
            }
            float alpha[4], rsum[4];
            #pragma unroll
            for (int r = 0; r < 4; ++r) {
                const float mn = fmaxf(m_r[t][r], rmax[r]);
                alpha[r] = __expf(m_r[t][r] - mn);
                m_r[t][r] = mn;
                rsum[r] = 0.0f;
            }
            #pragma unroll
            for (int n = 0; n < 4; ++n)
                #pragma unroll
                for (int r = 0; r < 4; ++r) {
                    p[n][r] = __expf(p[n][r] - m_r[t][r]);
                    rsum[r] += p[n][r];
                }
            #pragma unroll
            for (int r = 0; r < 4; ++r) {
                rsum[r] += __shfl_xor(rsum[r], 1, 64);
                rsum[r] += __shfl_xor(rsum[r], 2, 64);
                rsum[r] += __shfl_xor(rsum[r], 4, 64);
                rsum[r] += __shfl_xor(rsum[r], 8, 64);
                l_r[t][r] = l_r[t][r] * alpha[r] + rsum[r];
            }

            // ---- P bf16 -> LDS (C-layout); same wave re-reads as A ----
            #pragma unroll
            for (int n = 0; n < 4; ++n)
                #pragma unroll
                for (int r = 0; r < 4; ++r)
                    Pt[(rb + ly * 4 + r) * 72 + n * 16 + lx] = (__bf16)p[n][r];

            #pragma unroll
            for (int n = 0; n < 5; ++n)
                #pragma unroll
                for (int r = 0; r < 4; ++r) acc_o[t][n][r] *= alpha[r];

            // ---- PV ----
            bf16x8 ap[2];
            #pragma unroll
            for (int ks = 0; ks < 2; ++ks)
                ap[ks] = *(const bf16x8*)
                    &Pt[(rb + lx) * 72 + ks * 32 + ly * 8];
            __builtin_amdgcn_s_setprio(1);
            #pragma unroll
            for (int n = 0; n < 5; ++n) {
                f32x4 c = acc_o[t][n];
                #pragma unroll
                for (int ks = 0; ks < 2; ++ks) {
                    const bf16x8 bv = *(const bf16x8*)
                        &Vt[cur][(n * 16 + lx) * 64 +
                                 ((ks * 4 + ly) ^ (lx & 7)) * 8];
                    c = __builtin_amdgcn_mfma_f32_16x16x32_bf16(
                        ap[ks], bv, c, 0, 0, 0);
                }
                acc_o[t][n] = c;
            }
            __builtin_amdgcn_s_setprio(0);
        }
        cur ^= 1;
    }

    // ---- epilogue ----
    const int b = bh >> 4, h = bh & 15;
    #pragma unroll
    for (int t = 0; t < 2; ++t)
        #pragma unroll
        for (int r = 0; r < 4; ++r) {
            const int qrow = q0r + t * 64 + w * 16 + ly * 4 + r;
            const float inv = 1.0f / l_r[t][r];
            const size_t rowb =
                (size_t)b * T_ * DIM_ + (size_t)qrow * DIM_ + h * HD1_;
            #pragma unroll
            for (int n = 0; n < 4; ++n)
                Y[rowb + n * 16 + lx] = acc_o[t][n][r] * inv;
            if (lx == 0) Y[rowb + 64] = acc_o[t][4][r] * inv;
        }
}

// ---------------------------------------------------------------------------
// Workspace (65.4 MB, < proven 68.1 MB):
//  q/y [NELEM] f32 | k [NELEM] f32 (-> WcP after rotary) |
//  WcQKV [NP3_*KPP_] bf16 (-> QB|KB|q0f|k0f after QKV GEMM) | VT bf16
// ---------------------------------------------------------------------------
extern "C" void kernel_launch(void* const* d_in, const int* in_sizes, int n_in,
                              void* d_out, int out_size, void* d_ws, size_t ws_size,
                              hipStream_t stream)
{
    const float* x  = (const float*)d_in[0];
    const float* Wq = (const float*)d_in[1];
    const float* Wk = (const float*)d_in[2];
    const float* Wv = (const float*)d_in[3];
    const float* Wp = (const float*)d_in[4];

    float*  q     = (float*)d_ws;                       // also y
    float*  k     = q + NELEM;                          // also WcP space
    __bf16* WcQKV = (__bf16*)(k + NELEM);               // 21.9 MB
    __bf16* VT    = WcQKV + (size_t)NP3_ * KPP_;        // 9.44 MB

    // aliases into WcQKV (dead after QKV GEMM):
    __bf16* QB  = WcQKV;
    __bf16* KB  = QB + (size_t)NBH_ * T_ * 64;
    float*  q0f = (float*)(KB + (size_t)NBH_ * T_ * 64);
    float*  k0f = q0f + NBH_ * T_;
    // alias into k (dead after rotary):
    __bf16* WcP = (__bf16*)k;

    float* y   = q;
    float* out = (float*)d_out;

    dim3 blk(256);

    convert_w3<<<dim3(NP3_ * SEGS_ / 256), blk, 0, stream>>>(Wq, Wk, Wv, WcQKV);
    hipMemsetAsync(VT, 0, (size_t)NBH_ * VTR_ * T_ * 2, stream);
    gemm_qkv<<<dim3(864), blk, 0, stream>>>(x, WcQKV, q, k, VT);

    rotary2<<<dim3(2 * (B_ * T_ * H_) / 4), blk, 0, stream>>>(
        q, k, QB, KB, q0f, k0f);

    attn_mfma3<<<dim3(NBH_, T_ / 128), blk, 0, stream>>>(
        QB, KB, VT, q0f, k0f, y);

    convert_w<<<dim3((NP_ * SEGS_ + 255) / 256), blk, 0, stream>>>(Wp, WcP);
    gemm_out<<<dim3(288), blk, 0, stream>>>(y, WcP, out);
}